// Round 9
// baseline (631.287 us; speedup 1.0000x reference)
//
#include <hip/hip_runtime.h>
#include <hip/hip_bf16.h>
#include <hip/hip_fp16.h>

// Problem constants
#define BB 2
#define L2C 4
#define N2C 2048
#define L1C 9
#define N1C 8192
#define CINC 128
#define CTC 128
#define CSC 256
#define CORIGC 64
#define KC 3

#define OUT_XYZ_SIZE (BB*L1C*N1C*3)
#define FLT_BIG     3.402823466e38f

// knn LDS: 1024-seed chunks, padded group stride (16 seeds + 4 pad = 80B)
#define CHUNK   1024
#define GSTRIDE 20
#define NGROUPS 64             // 1024 seeds / 16
#define LDSF    (NGROUPS * GSTRIDE)   // 1280 floats per array (5 KB)

typedef __attribute__((ext_vector_type(8))) short bf16x8;
typedef __attribute__((ext_vector_type(4))) float f32x4;
typedef __attribute__((ext_vector_type(2))) float f32x2;
typedef __attribute__((ext_vector_type(4))) unsigned short u16x4;

#define MFMA16(a,b,c) __builtin_amdgcn_mfma_f32_16x16x32_bf16((a),(b),(c),0,0,0)

// ws layout (bytes):
//  tt   bf16     @ 0          : 6,291,456 * 2 = 12,582,912
//  nbr  u32      @ 12,582,912 :   442,368 * 4 =  1,769,472   (idx16<<16 | half(w))
//  WsH/WsL/W0H/W0L/W1H/W1L bf16 @ 14,352,384 : 6 * 49,152 * 2 = 589,824
//  bnp  f32[512] @ 14,942,208 : 2,048
//  total 14,944,256
#define WS_TT_OFF   0
#define WS_NBR_OFF  12582912
#define WS_W_OFF    14352384
#define WS_BNP_OFF  14942208

__device__ __forceinline__ unsigned short bf16_hi(float v) {
    __hip_bfloat16 h = __float2bfloat16(v);
    return *(unsigned short*)&h;
}
__device__ __forceinline__ float bf16_to_f(unsigned short u) {
    unsigned int x = ((unsigned int)u) << 16;
    return __uint_as_float(x);
}

// Packed distance for 2 seeds. Seeds are stored NEGATED in LDS so the
// subtraction becomes an add (bitwise identical: a + (-x) == a - x).
// contract(off) + same association ((dx*dx + dy*dy) + dz*dz) keeps distances
// bit-identical to the original scalar kernel -> identical top-3 selection.
__device__ __forceinline__ f32x2 d2pk(f32x2 nx, f32x2 ny, f32x2 nz,
                                      f32x2 av0, f32x2 av1, f32x2 av2) {
    #pragma clang fp contract(off)
    f32x2 dx = av0 + nx;
    f32x2 dy = av1 + ny;
    f32x2 dz = av2 + nz;
    return (dx * dx + dy * dy) + dz * dz;
}

// ---------------------------------------------------------------------------
// Kernel P: hi/lo bf16 splits of Ws/Wt0/Wt1 (each 49152 elems) + BN fold.
__global__ __launch_bounds__(256) void prep_kernel(const float* __restrict__ Wsm,
                                                   const float* __restrict__ Wt0,
                                                   const float* __restrict__ Wt1,
                                                   const float* __restrict__ gam,
                                                   const float* __restrict__ bet,
                                                   const float* __restrict__ mu,
                                                   const float* __restrict__ var,
                                                   unsigned short* __restrict__ WsH,
                                                   unsigned short* __restrict__ WsL,
                                                   unsigned short* __restrict__ W0H,
                                                   unsigned short* __restrict__ W0L,
                                                   unsigned short* __restrict__ W1H,
                                                   unsigned short* __restrict__ W1L,
                                                   float* __restrict__ bnp) {
    for (int i = blockIdx.x * 256 + threadIdx.x; i < 49152; i += gridDim.x * 256) {
        float a = Wsm[i]; unsigned short h = bf16_hi(a);
        WsH[i] = h; WsL[i] = bf16_hi(a - bf16_to_f(h));
        float b = Wt0[i]; h = bf16_hi(b);
        W0H[i] = h; W0L[i] = bf16_hi(b - bf16_to_f(h));
        float c = Wt1[i]; h = bf16_hi(c);
        W1H[i] = h; W1L[i] = bf16_hi(c - bf16_to_f(h));
    }
    if (blockIdx.x == 0) {
        int o = threadIdx.x;
        float sc = gam[o] / sqrtf(var[o] + 1e-5f);
        bnp[o]       = sc;
        bnp[CSC + o] = bet[o] - mu[o] * sc;
    }
}

// ---------------------------------------------------------------------------
// Kernel 1 (MFMA): tt[slice][k][n2][c] = relu(W1[k] @ relu(W0[k] @ feat[slice]))
// k on blockIdx.z (independent iterations) -> 768 blocks = 3/CU.
__global__ __launch_bounds__(256) void tt_kernel(const float* __restrict__ feat,
                                                 const unsigned short* __restrict__ W0H,
                                                 const unsigned short* __restrict__ W0L,
                                                 const unsigned short* __restrict__ W1H,
                                                 const unsigned short* __restrict__ W1L,
                                                 unsigned short* __restrict__ tt) {
    __shared__ unsigned short Bh[16 * 64 * 8];   // feat tile hi  (16 KB)
    __shared__ unsigned short Bl[16 * 64 * 8];   // feat tile lo
    __shared__ unsigned short Hh[16 * 64 * 8];   // layer-1 output hi
    const int t     = threadIdx.x;
    const int slice = blockIdx.y;
    const int k     = blockIdx.z;
    const int n0    = blockIdx.x * 64;
    const int lane  = t & 63;
    const int w     = t >> 6;
    const int l15   = lane & 15;
    const int quad  = lane >> 4;

    const float* f = feat + (size_t)slice * CINC * N2C;
    for (int i = 0; i < 32; ++i) {
        int idx = i * 256 + t;
        int c = idx >> 6, n = idx & 63;
        float v = f[(size_t)c * N2C + n0 + n];
        unsigned short h = bf16_hi(v);
        int bi = (((c >> 3) * 64) + n) * 8 + (c & 7);
        Bh[bi] = h;
        Bl[bi] = bf16_hi(v - bf16_to_f(h));
    }
    __syncthreads();

    unsigned short* ttg = tt + (size_t)slice * KC * N2C * CTC;
    const f32x4 zero = {0.f, 0.f, 0.f, 0.f};

    // ---- layer 1 ----
    f32x4 acc[2][4];
    for (int oi = 0; oi < 2; ++oi)
        for (int ni = 0; ni < 4; ++ni) acc[oi][ni] = zero;
    {
        const unsigned short* AH = W0H + (size_t)k * CTC * CINC;
        const unsigned short* AL = W0L + (size_t)k * CTC * CINC;
        for (int kst = 0; kst < 4; ++kst) {
            bf16x8 ah[2], al[2], bh[4], bl[4];
            #pragma unroll
            for (int oi = 0; oi < 2; ++oi) {
                int o = 32 * w + oi * 16 + l15;
                ah[oi] = *(const bf16x8*)(AH + (size_t)o * CINC + kst * 32 + quad * 8);
                al[oi] = *(const bf16x8*)(AL + (size_t)o * CINC + kst * 32 + quad * 8);
            }
            #pragma unroll
            for (int ni = 0; ni < 4; ++ni) {
                int n = ni * 16 + l15;
                int c8 = kst * 4 + quad;
                bh[ni] = *(const bf16x8*)&Bh[(c8 * 64 + n) * 8];
                bl[ni] = *(const bf16x8*)&Bl[(c8 * 64 + n) * 8];
            }
            #pragma unroll
            for (int oi = 0; oi < 2; ++oi)
                #pragma unroll
                for (int ni = 0; ni < 4; ++ni) {
                    acc[oi][ni] = MFMA16(ah[oi], bh[ni], acc[oi][ni]);
                    acc[oi][ni] = MFMA16(ah[oi], bl[ni], acc[oi][ni]);
                    acc[oi][ni] = MFMA16(al[oi], bh[ni], acc[oi][ni]);
                }
        }
    }
    #pragma unroll
    for (int oi = 0; oi < 2; ++oi)
        #pragma unroll
        for (int ni = 0; ni < 4; ++ni) {
            int n = ni * 16 + l15;
            int obase = 32 * w + oi * 16 + quad * 4;
            int ch = obase >> 3, jj = obase & 7;
            unsigned short* dst = &Hh[(ch * 64 + n) * 8 + jj];
            dst[0] = bf16_hi(fmaxf(acc[oi][ni][0], 0.f));
            dst[1] = bf16_hi(fmaxf(acc[oi][ni][1], 0.f));
            dst[2] = bf16_hi(fmaxf(acc[oi][ni][2], 0.f));
            dst[3] = bf16_hi(fmaxf(acc[oi][ni][3], 0.f));
        }
    __syncthreads();

    // ---- layer 2 ----
    f32x4 acc2[2][4];
    for (int oi = 0; oi < 2; ++oi)
        for (int ni = 0; ni < 4; ++ni) acc2[oi][ni] = zero;
    {
        const unsigned short* AH = W1H + (size_t)k * CTC * CTC;
        const unsigned short* AL = W1L + (size_t)k * CTC * CTC;
        for (int kst = 0; kst < 4; ++kst) {
            bf16x8 ah[2], al[2], bh[4];
            #pragma unroll
            for (int oi = 0; oi < 2; ++oi) {
                int o = 32 * w + oi * 16 + l15;
                ah[oi] = *(const bf16x8*)(AH + (size_t)o * CTC + kst * 32 + quad * 8);
                al[oi] = *(const bf16x8*)(AL + (size_t)o * CTC + kst * 32 + quad * 8);
            }
            #pragma unroll
            for (int ni = 0; ni < 4; ++ni) {
                int n = ni * 16 + l15;
                int c8 = kst * 4 + quad;
                bh[ni] = *(const bf16x8*)&Hh[(c8 * 64 + n) * 8];
            }
            #pragma unroll
            for (int oi = 0; oi < 2; ++oi)
                #pragma unroll
                for (int ni = 0; ni < 4; ++ni) {
                    acc2[oi][ni] = MFMA16(ah[oi], bh[ni], acc2[oi][ni]);
                    acc2[oi][ni] = MFMA16(al[oi], bh[ni], acc2[oi][ni]);
                }
        }
    }
    // relu + bf16 store: tt[k][n2][o], 4 consecutive o per lane -> 8B store
    #pragma unroll
    for (int oi = 0; oi < 2; ++oi)
        #pragma unroll
        for (int ni = 0; ni < 4; ++ni) {
            int n2 = n0 + ni * 16 + l15;
            int obase = 32 * w + oi * 16 + quad * 4;
            u16x4 vv;
            vv[0] = bf16_hi(fmaxf(acc2[oi][ni][0], 0.f));
            vv[1] = bf16_hi(fmaxf(acc2[oi][ni][1], 0.f));
            vv[2] = bf16_hi(fmaxf(acc2[oi][ni][2], 0.f));
            vv[3] = bf16_hi(fmaxf(acc2[oi][ni][3], 0.f));
            *(u16x4*)&ttg[((size_t)k * N2C + n2) * CTC + obase] = vv;
        }
}

// ---------------------------------------------------------------------------
// Kernel 2: 3-NN, 4 threads per anchor. grid (128 tiles of 64 anchors, 18 bt1).
// v7: two-pass group-min, GSTRIDE=20, 1024-seed chunks (15KB LDS, 8 blk/CU).
// Bit-identical selection to the original sequential scan (see v5/v6 notes).
__global__ __launch_bounds__(256, 8) void knn_kernel(const float* __restrict__ xyzs,
                                                     const float* __restrict__ oxyz,
                                                     unsigned int* __restrict__ nbr) {
    __shared__ __align__(16) float sx[LDSF];
    __shared__ __align__(16) float sy[LDSF];
    __shared__ __align__(16) float sz[LDSF];
    float* candd = sx;            // overlay after scan: [64][4][3] = 768 floats
    int*   candi = (int*)sy;
    const int t   = threadIdx.x;
    const int bt1 = blockIdx.y;
    const int b   = bt1 / L1C;
    const int t1  = bt1 % L1C + 1;
    int t2min = (t1 - 2) >> 1; if (t2min < 0) t2min = 0;
    int t2max = (t1 - 1) >> 1; if (t2max > 3) t2max = 3;
    const int S = (t2max - t2min + 1) * N2C;

    const int a  = t & 63;
    const int p  = t >> 6;
    const int n1 = blockIdx.x * 64 + a;
    const float* ap = oxyz + ((size_t)bt1 * N1C + n1) * 3;
    const float ax = ap[0], ay = ap[1], az = ap[2];
    const f32x2 ax2 = {ax, ax}, ay2 = {ay, ay}, az2 = {az, az};

    float b0 = FLT_BIG, b1 = FLT_BIG, b2 = FLT_BIG;
    int   i0 = 0, i1 = 0, i2 = 0;

    for (int cb = 0; cb < S; cb += CHUNK) {
        if (cb) __syncthreads();            // previous chunk fully consumed
        {
            int t2  = t2min + (cb >> 11);   // CHUNK divides plane size
            int off = cb & (N2C - 1);
            const float* base = xyzs + ((size_t)(b * L2C + t2) * N2C + off) * 3;
            for (int s = t; s < CHUNK; s += 256) {
                const float* pp = base + (size_t)s * 3;
                int li = (s >> 4) * GSTRIDE + (s & 15);
                sx[li] = -pp[0]; sy[li] = -pp[1]; sz[li] = -pp[2];
            }
        }
        __syncthreads();

        const int g0i = p * 16;             // this thread's 16 groups

        // ---- pass A: top-3 (group_min, group_seedbase) over 16 groups ----
        float gm0 = FLT_BIG, gm1 = FLT_BIG, gm2 = FLT_BIG;
        int   gs0 = g0i << 4, gs1 = g0i << 4, gs2 = g0i << 4;
        for (int g = g0i; g < g0i + 16; ++g) {
            const int gb = g * GSTRIDE;
            f32x2 dd[8];
            #pragma unroll
            for (int q = 0; q < 4; ++q) {
                float4 X = ((const float4*)&sx[gb])[q];
                float4 Y = ((const float4*)&sy[gb])[q];
                float4 Z = ((const float4*)&sz[gb])[q];
                f32x2 xlo = {X.x, X.y}, xhi = {X.z, X.w};
                f32x2 ylo = {Y.x, Y.y}, yhi = {Y.z, Y.w};
                f32x2 zlo = {Z.x, Z.y}, zhi = {Z.z, Z.w};
                dd[2 * q]     = d2pk(xlo, ylo, zlo, ax2, ay2, az2);
                dd[2 * q + 1] = d2pk(xhi, yhi, zhi, ax2, ay2, az2);
            }
            float e0 = fminf(dd[0][0], dd[0][1]);
            float e1 = fminf(dd[1][0], dd[1][1]);
            float e2 = fminf(dd[2][0], dd[2][1]);
            float e3 = fminf(dd[3][0], dd[3][1]);
            float e4 = fminf(dd[4][0], dd[4][1]);
            float e5 = fminf(dd[5][0], dd[5][1]);
            float e6 = fminf(dd[6][0], dd[6][1]);
            float e7 = fminf(dd[7][0], dd[7][1]);
            float f0 = fminf(e0, e1), f1 = fminf(e2, e3);
            float f2 = fminf(e4, e5), f3 = fminf(e6, e7);
            float m  = fminf(fminf(f0, f1), fminf(f2, f3));
            // branchless group insert (strict <); processing order = id order,
            // so earliest-kept == smallest base automatically on ties
            int sb = g << 4;
            bool c0 = m < gm0, c1 = m < gm1, c2 = m < gm2;
            int ns0 = c0 ? sb  : gs0;
            int ns1 = c0 ? gs0 : (c1 ? sb : gs1);
            int ns2 = c1 ? gs1 : (c2 ? sb : gs2);
            float nm0 = fminf(gm0, m);
            float nm1 = __builtin_amdgcn_fmed3f(gm0, gm1, m);
            float nm2 = __builtin_amdgcn_fmed3f(gm1, gm2, m);
            gm0 = nm0; gm1 = nm1; gm2 = nm2;
            gs0 = ns0; gs1 = ns1; gs2 = ns2;
        }

        // ---- pass B: exact per-seed insert over the 3 winning groups ----
        // sort the 3 seed-bases ascending (branchless min/max + sum trick)
        int lo01 = min(gs0, gs1), hi01 = max(gs0, gs1);
        int gA = min(lo01, gs2);
        int gC = max(hi01, gs2);
        int gB = (gs0 + gs1 + gs2) - gA - gC;

        #pragma unroll
        for (int v = 0; v < 3; ++v) {
            int sb = (v == 0) ? gA : ((v == 1) ? gB : gC);
            const int lb = (sb >> 4) * GSTRIDE;
            f32x2 dd[8];
            #pragma unroll
            for (int q = 0; q < 4; ++q) {
                float4 X = ((const float4*)&sx[lb])[q];
                float4 Y = ((const float4*)&sy[lb])[q];
                float4 Z = ((const float4*)&sz[lb])[q];
                f32x2 xlo = {X.x, X.y}, xhi = {X.z, X.w};
                f32x2 ylo = {Y.x, Y.y}, yhi = {Y.z, Y.w};
                f32x2 zlo = {Z.x, Z.y}, zhi = {Z.z, Z.w};
                dd[2 * q]     = d2pk(xlo, ylo, zlo, ax2, ay2, az2);
                dd[2 * q + 1] = d2pk(xhi, yhi, zhi, ax2, ay2, az2);
            }
            #pragma unroll
            for (int jp = 0; jp < 8; ++jp)
                #pragma unroll
                for (int h = 0; h < 2; ++h) {
                    float d = dd[jp][h];
                    int   s = cb + sb + jp * 2 + h;
                    bool c0 = d < b0, c1 = d < b1, c2 = d < b2;
                    int ni0 = c0 ? s  : i0;
                    int ni1 = c0 ? i0 : (c1 ? s : i1);
                    int ni2 = c1 ? i1 : (c2 ? s : i2);
                    float nb0 = fminf(b0, d);
                    float nb1 = __builtin_amdgcn_fmed3f(b0, b1, d);
                    float nb2 = __builtin_amdgcn_fmed3f(b1, b2, d);
                    b0 = nb0; b1 = nb1; b2 = nb2;
                    i0 = ni0; i1 = ni1; i2 = ni2;
                }
        }
    }
    __syncthreads();   // all scans done; sx/sy reusable as candidate store

    candd[(a * 4 + p) * 3 + 0] = b0; candi[(a * 4 + p) * 3 + 0] = i0;
    candd[(a * 4 + p) * 3 + 1] = b1; candi[(a * 4 + p) * 3 + 1] = i1;
    candd[(a * 4 + p) * 3 + 2] = b2; candi[(a * 4 + p) * 3 + 2] = i2;
    __syncthreads();

    if (t < 64) {
        float dd[12]; int ii[12];
        for (int q = 0; q < 12; ++q) { dd[q] = candd[t * 12 + q]; ii[q] = candi[t * 12 + q]; }
        for (int x = 1; x < 12; ++x) {
            float dv = dd[x]; int iv = ii[x]; int y = x - 1;
            while (y >= 0 && (dd[y] > dv || (dd[y] == dv && ii[y] > iv))) {
                dd[y + 1] = dd[y]; ii[y + 1] = ii[y]; --y;
            }
            dd[y + 1] = dv; ii[y + 1] = iv;
        }
        float w0 = 1.f / (dd[0] + 1e-8f);
        float w1 = 1.f / (dd[1] + 1e-8f);
        float w2 = 1.f / (dd[2] + 1e-8f);
        float wsum = (w0 + w1) + w2;
        float wv[3] = { w0 / wsum, w1 / wsum, w2 / wsum };
        size_t base = ((size_t)bt1 * N1C + blockIdx.x * 64 + t) * 3;
        #pragma unroll
        for (int j = 0; j < 3; ++j) {
            int s  = ii[j];
            int t2 = t2min + (s >> 11);
            int n2 = s & 2047;
            int kidx = t1 - 2 * t2 - 1;
            unsigned int idx16 = (unsigned int)(((b * L2C + t2) * KC + kidx) * N2C + n2);
            unsigned short hb = __half_as_ushort(__float2half(wv[j]));
            nbr[base + j] = (idx16 << 16) | (unsigned int)hb;
        }
    }
}

// ---------------------------------------------------------------------------
// Kernel 3 (MFMA): gather-interp + concat + GEMM(o=256, k=192) + BN + ReLU.
// v2: K-PHASE-SPLIT staging. K=192 splits at c=128: interp channels (c8 0..15)
// feed kst 0..3; ofeat channels (c8 16..23) feed kst 4..5. Stage interp ->
// GEMM kst0-3 -> barrier -> stage ofeat into the SAME buffer -> GEMM kst4-5.
// LDS 48KB -> 32KB => 3 -> 5 blocks/CU (+66% waves to hide the interp
// gather-chain latency). MFMA sequence/operands unchanged -> bit-identical.
__global__ __launch_bounds__(256, 5) void out_kernel(const float* __restrict__ ofeat,
                                                     const unsigned short* __restrict__ WsH,
                                                     const unsigned short* __restrict__ WsL,
                                                     const unsigned short* __restrict__ tt,
                                                     const unsigned int* __restrict__ nbr,
                                                     const float* __restrict__ bnp,
                                                     float* __restrict__ out) {
    __shared__ unsigned short xh[16 * 64 * 8];   // x tile hi, K-blocked (16 KB)
    __shared__ unsigned short xl[16 * 64 * 8];   // x tile lo
    const int t    = threadIdx.x;
    const int bt1  = blockIdx.y;
    const int n0   = blockIdx.x * 64;
    const int w    = t >> 6;
    const int lane = t & 63;
    const int l15  = lane & 15;
    const int quad = lane >> 4;

    const f32x4 zero = {0.f, 0.f, 0.f, 0.f};
    f32x4 acc[4][4];
    for (int mi = 0; mi < 4; ++mi)
        for (int oi = 0; oi < 4; ++oi) acc[mi][oi] = zero;

    // ---- phase 1 staging: interp rows c=0..127 (c8 0..15) ----
    // lane handles channel pair (2*lane, 2*lane+1)
    const int c0 = 2 * lane;
    for (int nn = 0; nn < 16; ++nn) {
        int n = w * 16 + nn;
        size_t kb = ((size_t)bt1 * N1C + n0 + n) * 3;
        unsigned int u0 = nbr[kb], u1 = nbr[kb + 1], u2 = nbr[kb + 2];
        const unsigned short* p0 = tt + (size_t)(u0 >> 16) * CTC;
        const unsigned short* p1 = tt + (size_t)(u1 >> 16) * CTC;
        const unsigned short* p2 = tt + (size_t)(u2 >> 16) * CTC;
        float q0 = __half2float(__ushort_as_half((unsigned short)(u0 & 0xffffu)));
        float q1 = __half2float(__ushort_as_half((unsigned short)(u1 & 0xffffu)));
        float q2 = __half2float(__ushort_as_half((unsigned short)(u2 & 0xffffu)));
        unsigned int g0 = *(const unsigned int*)(p0 + c0);
        unsigned int g1 = *(const unsigned int*)(p1 + c0);
        unsigned int g2 = *(const unsigned int*)(p2 + c0);
        float vE = (bf16_to_f((unsigned short)(g0 & 0xffffu)) * q0
                  + bf16_to_f((unsigned short)(g1 & 0xffffu)) * q1)
                  + bf16_to_f((unsigned short)(g2 & 0xffffu)) * q2;
        float vO = (bf16_to_f((unsigned short)(g0 >> 16)) * q0
                  + bf16_to_f((unsigned short)(g1 >> 16)) * q1)
                  + bf16_to_f((unsigned short)(g2 >> 16)) * q2;
        int bi = (((c0 >> 3) * 64) + n) * 8 + (c0 & 7);   // even -> +1 adjacent
        unsigned short hE = bf16_hi(vE), hO = bf16_hi(vO);
        *(unsigned int*)&xh[bi] = (unsigned int)hE | ((unsigned int)hO << 16);
        unsigned short lE = bf16_hi(vE - bf16_to_f(hE));
        unsigned short lO = bf16_hi(vO - bf16_to_f(hO));
        *(unsigned int*)&xl[bi] = (unsigned int)lE | ((unsigned int)lO << 16);
    }
    __syncthreads();

    // ---- phase 1 GEMM: kst 0..3 (c8 0..15) ----
    for (int kst = 0; kst < 4; ++kst) {
        bf16x8 ah[4], al[4], bh[4], bl[4];
        #pragma unroll
        for (int mi = 0; mi < 4; ++mi) {
            int n = mi * 16 + l15;
            int c8 = kst * 4 + quad;
            ah[mi] = *(const bf16x8*)&xh[(c8 * 64 + n) * 8];
            al[mi] = *(const bf16x8*)&xl[(c8 * 64 + n) * 8];
        }
        #pragma unroll
        for (int oi = 0; oi < 4; ++oi) {
            int o = w * 64 + oi * 16 + l15;
            bh[oi] = *(const bf16x8*)(WsH + (size_t)o * 192 + kst * 32 + quad * 8);
            bl[oi] = *(const bf16x8*)(WsL + (size_t)o * 192 + kst * 32 + quad * 8);
        }
        #pragma unroll
        for (int mi = 0; mi < 4; ++mi)
            #pragma unroll
            for (int oi = 0; oi < 4; ++oi) {
                acc[mi][oi] = MFMA16(ah[mi], bh[oi], acc[mi][oi]);
                acc[mi][oi] = MFMA16(ah[mi], bl[oi], acc[mi][oi]);
                acc[mi][oi] = MFMA16(al[mi], bh[oi], acc[mi][oi]);
            }
    }
    __syncthreads();   // phase-1 reads done; buffer reusable

    // ---- phase 2 staging: original_features c=128..191 (c8' 0..7) ----
    {
        const float* ofp = ofeat + (size_t)bt1 * CORIGC * N1C;
        for (int i = 0; i < 16; ++i) {
            int idx = i * 256 + t;
            int cp = idx >> 6, n = idx & 63;   // cp = c-128 in 0..63
            float v = ofp[(size_t)cp * N1C + n0 + n];
            int bi = (((cp >> 3) * 64) + n) * 8 + (cp & 7);
            unsigned short h = bf16_hi(v);
            xh[bi] = h; xl[bi] = bf16_hi(v - bf16_to_f(h));
        }
    }
    __syncthreads();

    // ---- phase 2 GEMM: kst 4..5 (c8' 0..7) ----
    for (int kst = 4; kst < 6; ++kst) {
        bf16x8 ah[4], al[4], bh[4], bl[4];
        #pragma unroll
        for (int mi = 0; mi < 4; ++mi) {
            int n = mi * 16 + l15;
            int c8p = (kst - 4) * 4 + quad;
            ah[mi] = *(const bf16x8*)&xh[(c8p * 64 + n) * 8];
            al[mi] = *(const bf16x8*)&xl[(c8p * 64 + n) * 8];
        }
        #pragma unroll
        for (int oi = 0; oi < 4; ++oi) {
            int o = w * 64 + oi * 16 + l15;
            bh[oi] = *(const bf16x8*)(WsH + (size_t)o * 192 + kst * 32 + quad * 8);
            bl[oi] = *(const bf16x8*)(WsL + (size_t)o * 192 + kst * 32 + quad * 8);
        }
        #pragma unroll
        for (int mi = 0; mi < 4; ++mi)
            #pragma unroll
            for (int oi = 0; oi < 4; ++oi) {
                acc[mi][oi] = MFMA16(ah[mi], bh[oi], acc[mi][oi]);
                acc[mi][oi] = MFMA16(ah[mi], bl[oi], acc[mi][oi]);
                acc[mi][oi] = MFMA16(al[mi], bh[oi], acc[mi][oi]);
            }
    }

    float* outp = out + OUT_XYZ_SIZE + (size_t)bt1 * CSC * N1C;
    #pragma unroll
    for (int oi = 0; oi < 4; ++oi) {
        int o = w * 64 + oi * 16 + l15;
        float sc = bnp[o], sh = bnp[CSC + o];
        #pragma unroll
        for (int mi = 0; mi < 4; ++mi) {
            int nb = n0 + mi * 16 + quad * 4;
            f32x4 y;
            y[0] = fmaxf(acc[mi][oi][0] * sc + sh, 0.f);
            y[1] = fmaxf(acc[mi][oi][1] * sc + sh, 0.f);
            y[2] = fmaxf(acc[mi][oi][2] * sc + sh, 0.f);
            y[3] = fmaxf(acc[mi][oi][3] * sc + sh, 0.f);
            *(f32x4*)&outp[(size_t)o * N1C + nb] = y;
        }
    }
}

// ---------------------------------------------------------------------------
extern "C" void kernel_launch(void* const* d_in, const int* in_sizes, int n_in,
                              void* d_out, int out_size, void* d_ws, size_t ws_size,
                              hipStream_t stream) {
    const float* xyzs  = (const float*)d_in[0];
    const float* oxyz  = (const float*)d_in[1];
    const float* feat  = (const float*)d_in[2];
    const float* ofeat = (const float*)d_in[3];
    const float* Wt0   = (const float*)d_in[4];
    const float* Wt1   = (const float*)d_in[5];
    const float* Wsm   = (const float*)d_in[6];
    const float* gam   = (const float*)d_in[7];
    const float* bet   = (const float*)d_in[8];
    const float* mu    = (const float*)d_in[9];
    const float* var   = (const float*)d_in[10];
    float* out = (float*)d_out;
    char*  wsb = (char*)d_ws;

    unsigned short* tt  = (unsigned short*)(wsb + WS_TT_OFF);
    unsigned int*   nbr = (unsigned int*)(wsb + WS_NBR_OFF);
    unsigned short* WsH = (unsigned short*)(wsb + WS_W_OFF);
    unsigned short* WsL = WsH + 49152;
    unsigned short* W0H = WsL + 49152;
    unsigned short* W0L = W0H + 49152;
    unsigned short* W1H = W0L + 49152;
    unsigned short* W1L = W1H + 49152;
    float*          bnp = (float*)(wsb + WS_BNP_OFF);

    // Output 0: exact passthrough
    hipMemcpyAsync(out, oxyz, (size_t)OUT_XYZ_SIZE * sizeof(float),
                   hipMemcpyDeviceToDevice, stream);

    hipLaunchKernelGGL(prep_kernel, dim3(64), dim3(256), 0, stream,
                       Wsm, Wt0, Wt1, gam, bet, mu, var,
                       WsH, WsL, W0H, W0L, W1H, W1L, bnp);
    hipLaunchKernelGGL(tt_kernel, dim3(32, BB * L2C, KC), dim3(256), 0, stream,
                       feat, W0H, W0L, W1H, W1L, tt);
    hipLaunchKernelGGL(knn_kernel, dim3(128, BB * L1C), dim3(256), 0, stream,
                       xyzs, oxyz, nbr);
    hipLaunchKernelGGL(out_kernel, dim3(128, BB * L1C), dim3(256), 0, stream,
                       ofeat, WsH, WsL, tt, nbr, bnp, out);
}

// Round 10
// 469.712 us; speedup vs baseline: 1.3440x; 1.3440x over previous
//
#include <hip/hip_runtime.h>
#include <hip/hip_bf16.h>
#include <hip/hip_fp16.h>

// Problem constants
#define BB 2
#define L2C 4
#define N2C 2048
#define L1C 9
#define N1C 8192
#define CINC 128
#define CTC 128
#define CSC 256
#define CORIGC 64
#define KC 3

#define OUT_XYZ_SIZE (BB*L1C*N1C*3)
#define FLT_BIG     3.402823466e38f

// knn LDS: 1024-seed chunks, padded group stride (16 seeds + 4 pad = 80B)
#define CHUNK   1024
#define GSTRIDE 20
#define NGROUPS 64             // 1024 seeds / 16
#define LDSF    (NGROUPS * GSTRIDE)   // 1280 floats per array (5 KB)

typedef __attribute__((ext_vector_type(8))) short bf16x8;
typedef __attribute__((ext_vector_type(4))) float f32x4;
typedef __attribute__((ext_vector_type(2))) float f32x2;
typedef __attribute__((ext_vector_type(4))) unsigned short u16x4;

#define MFMA16(a,b,c) __builtin_amdgcn_mfma_f32_16x16x32_bf16((a),(b),(c),0,0,0)

// ws layout (bytes):
//  tt   bf16     @ 0          : 6,291,456 * 2 = 12,582,912
//  nbr  u32      @ 12,582,912 :   442,368 * 4 =  1,769,472   (idx16<<16 | half(w))
//  WsH/WsL/W0H/W0L/W1H/W1L bf16 @ 14,352,384 : 6 * 49,152 * 2 = 589,824
//  bnp  f32[512] @ 14,942,208 : 2,048
//  total 14,944,256
#define WS_TT_OFF   0
#define WS_NBR_OFF  12582912
#define WS_W_OFF    14352384
#define WS_BNP_OFF  14942208

__device__ __forceinline__ unsigned short bf16_hi(float v) {
    __hip_bfloat16 h = __float2bfloat16(v);
    return *(unsigned short*)&h;
}
__device__ __forceinline__ float bf16_to_f(unsigned short u) {
    unsigned int x = ((unsigned int)u) << 16;
    return __uint_as_float(x);
}

// Packed distance for 2 seeds. Seeds are stored NEGATED in LDS so the
// subtraction becomes an add (bitwise identical: a + (-x) == a - x).
// contract(off) + same association ((dx*dx + dy*dy) + dz*dz) keeps distances
// bit-identical to the original scalar kernel -> identical top-3 selection.
__device__ __forceinline__ f32x2 d2pk(f32x2 nx, f32x2 ny, f32x2 nz,
                                      f32x2 av0, f32x2 av1, f32x2 av2) {
    #pragma clang fp contract(off)
    f32x2 dx = av0 + nx;
    f32x2 dy = av1 + ny;
    f32x2 dz = av2 + nz;
    return (dx * dx + dy * dy) + dz * dz;
}

// ---------------------------------------------------------------------------
// Kernel P: hi/lo bf16 splits of Ws/Wt0/Wt1 (each 49152 elems) + BN fold.
__global__ __launch_bounds__(256) void prep_kernel(const float* __restrict__ Wsm,
                                                   const float* __restrict__ Wt0,
                                                   const float* __restrict__ Wt1,
                                                   const float* __restrict__ gam,
                                                   const float* __restrict__ bet,
                                                   const float* __restrict__ mu,
                                                   const float* __restrict__ var,
                                                   unsigned short* __restrict__ WsH,
                                                   unsigned short* __restrict__ WsL,
                                                   unsigned short* __restrict__ W0H,
                                                   unsigned short* __restrict__ W0L,
                                                   unsigned short* __restrict__ W1H,
                                                   unsigned short* __restrict__ W1L,
                                                   float* __restrict__ bnp) {
    for (int i = blockIdx.x * 256 + threadIdx.x; i < 49152; i += gridDim.x * 256) {
        float a = Wsm[i]; unsigned short h = bf16_hi(a);
        WsH[i] = h; WsL[i] = bf16_hi(a - bf16_to_f(h));
        float b = Wt0[i]; h = bf16_hi(b);
        W0H[i] = h; W0L[i] = bf16_hi(b - bf16_to_f(h));
        float c = Wt1[i]; h = bf16_hi(c);
        W1H[i] = h; W1L[i] = bf16_hi(c - bf16_to_f(h));
    }
    if (blockIdx.x == 0) {
        int o = threadIdx.x;
        float sc = gam[o] / sqrtf(var[o] + 1e-5f);
        bnp[o]       = sc;
        bnp[CSC + o] = bet[o] - mu[o] * sc;
    }
}

// ---------------------------------------------------------------------------
// Kernel 1 (MFMA): tt[slice][k][n2][c] = relu(W1[k] @ relu(W0[k] @ feat[slice]))
// k on blockIdx.z (independent iterations) -> 768 blocks = 3/CU.
__global__ __launch_bounds__(256) void tt_kernel(const float* __restrict__ feat,
                                                 const unsigned short* __restrict__ W0H,
                                                 const unsigned short* __restrict__ W0L,
                                                 const unsigned short* __restrict__ W1H,
                                                 const unsigned short* __restrict__ W1L,
                                                 unsigned short* __restrict__ tt) {
    __shared__ unsigned short Bh[16 * 64 * 8];   // feat tile hi  (16 KB)
    __shared__ unsigned short Bl[16 * 64 * 8];   // feat tile lo
    __shared__ unsigned short Hh[16 * 64 * 8];   // layer-1 output hi
    const int t     = threadIdx.x;
    const int slice = blockIdx.y;
    const int k     = blockIdx.z;
    const int n0    = blockIdx.x * 64;
    const int lane  = t & 63;
    const int w     = t >> 6;
    const int l15   = lane & 15;
    const int quad  = lane >> 4;

    const float* f = feat + (size_t)slice * CINC * N2C;
    for (int i = 0; i < 32; ++i) {
        int idx = i * 256 + t;
        int c = idx >> 6, n = idx & 63;
        float v = f[(size_t)c * N2C + n0 + n];
        unsigned short h = bf16_hi(v);
        int bi = (((c >> 3) * 64) + n) * 8 + (c & 7);
        Bh[bi] = h;
        Bl[bi] = bf16_hi(v - bf16_to_f(h));
    }
    __syncthreads();

    unsigned short* ttg = tt + (size_t)slice * KC * N2C * CTC;
    const f32x4 zero = {0.f, 0.f, 0.f, 0.f};

    // ---- layer 1 ----
    f32x4 acc[2][4];
    for (int oi = 0; oi < 2; ++oi)
        for (int ni = 0; ni < 4; ++ni) acc[oi][ni] = zero;
    {
        const unsigned short* AH = W0H + (size_t)k * CTC * CINC;
        const unsigned short* AL = W0L + (size_t)k * CTC * CINC;
        for (int kst = 0; kst < 4; ++kst) {
            bf16x8 ah[2], al[2], bh[4], bl[4];
            #pragma unroll
            for (int oi = 0; oi < 2; ++oi) {
                int o = 32 * w + oi * 16 + l15;
                ah[oi] = *(const bf16x8*)(AH + (size_t)o * CINC + kst * 32 + quad * 8);
                al[oi] = *(const bf16x8*)(AL + (size_t)o * CINC + kst * 32 + quad * 8);
            }
            #pragma unroll
            for (int ni = 0; ni < 4; ++ni) {
                int n = ni * 16 + l15;
                int c8 = kst * 4 + quad;
                bh[ni] = *(const bf16x8*)&Bh[(c8 * 64 + n) * 8];
                bl[ni] = *(const bf16x8*)&Bl[(c8 * 64 + n) * 8];
            }
            #pragma unroll
            for (int oi = 0; oi < 2; ++oi)
                #pragma unroll
                for (int ni = 0; ni < 4; ++ni) {
                    acc[oi][ni] = MFMA16(ah[oi], bh[ni], acc[oi][ni]);
                    acc[oi][ni] = MFMA16(ah[oi], bl[ni], acc[oi][ni]);
                    acc[oi][ni] = MFMA16(al[oi], bh[ni], acc[oi][ni]);
                }
        }
    }
    #pragma unroll
    for (int oi = 0; oi < 2; ++oi)
        #pragma unroll
        for (int ni = 0; ni < 4; ++ni) {
            int n = ni * 16 + l15;
            int obase = 32 * w + oi * 16 + quad * 4;
            int ch = obase >> 3, jj = obase & 7;
            unsigned short* dst = &Hh[(ch * 64 + n) * 8 + jj];
            dst[0] = bf16_hi(fmaxf(acc[oi][ni][0], 0.f));
            dst[1] = bf16_hi(fmaxf(acc[oi][ni][1], 0.f));
            dst[2] = bf16_hi(fmaxf(acc[oi][ni][2], 0.f));
            dst[3] = bf16_hi(fmaxf(acc[oi][ni][3], 0.f));
        }
    __syncthreads();

    // ---- layer 2 ----
    f32x4 acc2[2][4];
    for (int oi = 0; oi < 2; ++oi)
        for (int ni = 0; ni < 4; ++ni) acc2[oi][ni] = zero;
    {
        const unsigned short* AH = W1H + (size_t)k * CTC * CTC;
        const unsigned short* AL = W1L + (size_t)k * CTC * CTC;
        for (int kst = 0; kst < 4; ++kst) {
            bf16x8 ah[2], al[2], bh[4];
            #pragma unroll
            for (int oi = 0; oi < 2; ++oi) {
                int o = 32 * w + oi * 16 + l15;
                ah[oi] = *(const bf16x8*)(AH + (size_t)o * CTC + kst * 32 + quad * 8);
                al[oi] = *(const bf16x8*)(AL + (size_t)o * CTC + kst * 32 + quad * 8);
            }
            #pragma unroll
            for (int ni = 0; ni < 4; ++ni) {
                int n = ni * 16 + l15;
                int c8 = kst * 4 + quad;
                bh[ni] = *(const bf16x8*)&Hh[(c8 * 64 + n) * 8];
            }
            #pragma unroll
            for (int oi = 0; oi < 2; ++oi)
                #pragma unroll
                for (int ni = 0; ni < 4; ++ni) {
                    acc2[oi][ni] = MFMA16(ah[oi], bh[ni], acc2[oi][ni]);
                    acc2[oi][ni] = MFMA16(al[oi], bh[ni], acc2[oi][ni]);
                }
        }
    }
    // relu + bf16 store: tt[k][n2][o], 4 consecutive o per lane -> 8B store
    #pragma unroll
    for (int oi = 0; oi < 2; ++oi)
        #pragma unroll
        for (int ni = 0; ni < 4; ++ni) {
            int n2 = n0 + ni * 16 + l15;
            int obase = 32 * w + oi * 16 + quad * 4;
            u16x4 vv;
            vv[0] = bf16_hi(fmaxf(acc2[oi][ni][0], 0.f));
            vv[1] = bf16_hi(fmaxf(acc2[oi][ni][1], 0.f));
            vv[2] = bf16_hi(fmaxf(acc2[oi][ni][2], 0.f));
            vv[3] = bf16_hi(fmaxf(acc2[oi][ni][3], 0.f));
            *(u16x4*)&ttg[((size_t)k * N2C + n2) * CTC + obase] = vv;
        }
}

// ---------------------------------------------------------------------------
// Kernel 2: 3-NN, 4 threads per anchor. grid (128 tiles of 64 anchors, 18 bt1).
// v7: two-pass group-min, GSTRIDE=20, 1024-seed chunks (15KB LDS, 8 blk/CU).
// Bit-identical selection to the original sequential scan (see v5/v6 notes).
__global__ __launch_bounds__(256, 8) void knn_kernel(const float* __restrict__ xyzs,
                                                     const float* __restrict__ oxyz,
                                                     unsigned int* __restrict__ nbr) {
    __shared__ __align__(16) float sx[LDSF];
    __shared__ __align__(16) float sy[LDSF];
    __shared__ __align__(16) float sz[LDSF];
    float* candd = sx;            // overlay after scan: [64][4][3] = 768 floats
    int*   candi = (int*)sy;
    const int t   = threadIdx.x;
    const int bt1 = blockIdx.y;
    const int b   = bt1 / L1C;
    const int t1  = bt1 % L1C + 1;
    int t2min = (t1 - 2) >> 1; if (t2min < 0) t2min = 0;
    int t2max = (t1 - 1) >> 1; if (t2max > 3) t2max = 3;
    const int S = (t2max - t2min + 1) * N2C;

    const int a  = t & 63;
    const int p  = t >> 6;
    const int n1 = blockIdx.x * 64 + a;
    const float* ap = oxyz + ((size_t)bt1 * N1C + n1) * 3;
    const float ax = ap[0], ay = ap[1], az = ap[2];
    const f32x2 ax2 = {ax, ax}, ay2 = {ay, ay}, az2 = {az, az};

    float b0 = FLT_BIG, b1 = FLT_BIG, b2 = FLT_BIG;
    int   i0 = 0, i1 = 0, i2 = 0;

    for (int cb = 0; cb < S; cb += CHUNK) {
        if (cb) __syncthreads();            // previous chunk fully consumed
        {
            int t2  = t2min + (cb >> 11);   // CHUNK divides plane size
            int off = cb & (N2C - 1);
            const float* base = xyzs + ((size_t)(b * L2C + t2) * N2C + off) * 3;
            for (int s = t; s < CHUNK; s += 256) {
                const float* pp = base + (size_t)s * 3;
                int li = (s >> 4) * GSTRIDE + (s & 15);
                sx[li] = -pp[0]; sy[li] = -pp[1]; sz[li] = -pp[2];
            }
        }
        __syncthreads();

        const int g0i = p * 16;             // this thread's 16 groups

        // ---- pass A: top-3 (group_min, group_seedbase) over 16 groups ----
        float gm0 = FLT_BIG, gm1 = FLT_BIG, gm2 = FLT_BIG;
        int   gs0 = g0i << 4, gs1 = g0i << 4, gs2 = g0i << 4;
        for (int g = g0i; g < g0i + 16; ++g) {
            const int gb = g * GSTRIDE;
            f32x2 dd[8];
            #pragma unroll
            for (int q = 0; q < 4; ++q) {
                float4 X = ((const float4*)&sx[gb])[q];
                float4 Y = ((const float4*)&sy[gb])[q];
                float4 Z = ((const float4*)&sz[gb])[q];
                f32x2 xlo = {X.x, X.y}, xhi = {X.z, X.w};
                f32x2 ylo = {Y.x, Y.y}, yhi = {Y.z, Y.w};
                f32x2 zlo = {Z.x, Z.y}, zhi = {Z.z, Z.w};
                dd[2 * q]     = d2pk(xlo, ylo, zlo, ax2, ay2, az2);
                dd[2 * q + 1] = d2pk(xhi, yhi, zhi, ax2, ay2, az2);
            }
            float e0 = fminf(dd[0][0], dd[0][1]);
            float e1 = fminf(dd[1][0], dd[1][1]);
            float e2 = fminf(dd[2][0], dd[2][1]);
            float e3 = fminf(dd[3][0], dd[3][1]);
            float e4 = fminf(dd[4][0], dd[4][1]);
            float e5 = fminf(dd[5][0], dd[5][1]);
            float e6 = fminf(dd[6][0], dd[6][1]);
            float e7 = fminf(dd[7][0], dd[7][1]);
            float f0 = fminf(e0, e1), f1 = fminf(e2, e3);
            float f2 = fminf(e4, e5), f3 = fminf(e6, e7);
            float m  = fminf(fminf(f0, f1), fminf(f2, f3));
            // branchless group insert (strict <); processing order = id order,
            // so earliest-kept == smallest base automatically on ties
            int sb = g << 4;
            bool c0 = m < gm0, c1 = m < gm1, c2 = m < gm2;
            int ns0 = c0 ? sb  : gs0;
            int ns1 = c0 ? gs0 : (c1 ? sb : gs1);
            int ns2 = c1 ? gs1 : (c2 ? sb : gs2);
            float nm0 = fminf(gm0, m);
            float nm1 = __builtin_amdgcn_fmed3f(gm0, gm1, m);
            float nm2 = __builtin_amdgcn_fmed3f(gm1, gm2, m);
            gm0 = nm0; gm1 = nm1; gm2 = nm2;
            gs0 = ns0; gs1 = ns1; gs2 = ns2;
        }

        // ---- pass B: exact per-seed insert over the 3 winning groups ----
        // sort the 3 seed-bases ascending (branchless min/max + sum trick)
        int lo01 = min(gs0, gs1), hi01 = max(gs0, gs1);
        int gA = min(lo01, gs2);
        int gC = max(hi01, gs2);
        int gB = (gs0 + gs1 + gs2) - gA - gC;

        #pragma unroll
        for (int v = 0; v < 3; ++v) {
            int sb = (v == 0) ? gA : ((v == 1) ? gB : gC);
            const int lb = (sb >> 4) * GSTRIDE;
            f32x2 dd[8];
            #pragma unroll
            for (int q = 0; q < 4; ++q) {
                float4 X = ((const float4*)&sx[lb])[q];
                float4 Y = ((const float4*)&sy[lb])[q];
                float4 Z = ((const float4*)&sz[lb])[q];
                f32x2 xlo = {X.x, X.y}, xhi = {X.z, X.w};
                f32x2 ylo = {Y.x, Y.y}, yhi = {Y.z, Y.w};
                f32x2 zlo = {Z.x, Z.y}, zhi = {Z.z, Z.w};
                dd[2 * q]     = d2pk(xlo, ylo, zlo, ax2, ay2, az2);
                dd[2 * q + 1] = d2pk(xhi, yhi, zhi, ax2, ay2, az2);
            }
            #pragma unroll
            for (int jp = 0; jp < 8; ++jp)
                #pragma unroll
                for (int h = 0; h < 2; ++h) {
                    float d = dd[jp][h];
                    int   s = cb + sb + jp * 2 + h;
                    bool c0 = d < b0, c1 = d < b1, c2 = d < b2;
                    int ni0 = c0 ? s  : i0;
                    int ni1 = c0 ? i0 : (c1 ? s : i1);
                    int ni2 = c1 ? i1 : (c2 ? s : i2);
                    float nb0 = fminf(b0, d);
                    float nb1 = __builtin_amdgcn_fmed3f(b0, b1, d);
                    float nb2 = __builtin_amdgcn_fmed3f(b1, b2, d);
                    b0 = nb0; b1 = nb1; b2 = nb2;
                    i0 = ni0; i1 = ni1; i2 = ni2;
                }
        }
    }
    __syncthreads();   // all scans done; sx/sy reusable as candidate store

    candd[(a * 4 + p) * 3 + 0] = b0; candi[(a * 4 + p) * 3 + 0] = i0;
    candd[(a * 4 + p) * 3 + 1] = b1; candi[(a * 4 + p) * 3 + 1] = i1;
    candd[(a * 4 + p) * 3 + 2] = b2; candi[(a * 4 + p) * 3 + 2] = i2;
    __syncthreads();

    if (t < 64) {
        float dd[12]; int ii[12];
        for (int q = 0; q < 12; ++q) { dd[q] = candd[t * 12 + q]; ii[q] = candi[t * 12 + q]; }
        for (int x = 1; x < 12; ++x) {
            float dv = dd[x]; int iv = ii[x]; int y = x - 1;
            while (y >= 0 && (dd[y] > dv || (dd[y] == dv && ii[y] > iv))) {
                dd[y + 1] = dd[y]; ii[y + 1] = ii[y]; --y;
            }
            dd[y + 1] = dv; ii[y + 1] = iv;
        }
        float w0 = 1.f / (dd[0] + 1e-8f);
        float w1 = 1.f / (dd[1] + 1e-8f);
        float w2 = 1.f / (dd[2] + 1e-8f);
        float wsum = (w0 + w1) + w2;
        float wv[3] = { w0 / wsum, w1 / wsum, w2 / wsum };
        size_t base = ((size_t)bt1 * N1C + blockIdx.x * 64 + t) * 3;
        #pragma unroll
        for (int j = 0; j < 3; ++j) {
            int s  = ii[j];
            int t2 = t2min + (s >> 11);
            int n2 = s & 2047;
            int kidx = t1 - 2 * t2 - 1;
            unsigned int idx16 = (unsigned int)(((b * L2C + t2) * KC + kidx) * N2C + n2);
            unsigned short hb = __half_as_ushort(__float2half(wv[j]));
            nbr[base + j] = (idx16 << 16) | (unsigned int)hb;
        }
    }
}

// ---------------------------------------------------------------------------
// Kernel 3 (MFMA): gather-interp + concat + GEMM(o=256, k=192) + BN + ReLU.
// v3 = v2 K-phase-split staging, but WITHOUT the min-waves launch bound.
// Round-9 PMC: __launch_bounds__(256,5) capped VGPR at ~102 < the ~128-VGPR
// working set (acc[4][4] f32x4 = 64 + operand tile = 64) -> accumulator
// spilled to scratch: VGPR_Count=48, WRITE 662MB (output is 151MB), MfmaUtil
// 5.7%. Unconstrained, compiler allocates ~130-160 VGPR (no spill) -> ~4
// blocks/CU (VGPR-bound), still >= the old 3 (48KB-LDS version).
__global__ __launch_bounds__(256) void out_kernel(const float* __restrict__ ofeat,
                                                  const unsigned short* __restrict__ WsH,
                                                  const unsigned short* __restrict__ WsL,
                                                  const unsigned short* __restrict__ tt,
                                                  const unsigned int* __restrict__ nbr,
                                                  const float* __restrict__ bnp,
                                                  float* __restrict__ out) {
    __shared__ unsigned short xh[16 * 64 * 8];   // x tile hi, K-blocked (16 KB)
    __shared__ unsigned short xl[16 * 64 * 8];   // x tile lo
    const int t    = threadIdx.x;
    const int bt1  = blockIdx.y;
    const int n0   = blockIdx.x * 64;
    const int w    = t >> 6;
    const int lane = t & 63;
    const int l15  = lane & 15;
    const int quad = lane >> 4;

    const f32x4 zero = {0.f, 0.f, 0.f, 0.f};
    f32x4 acc[4][4];
    for (int mi = 0; mi < 4; ++mi)
        for (int oi = 0; oi < 4; ++oi) acc[mi][oi] = zero;

    // ---- phase 1 staging: interp rows c=0..127 (c8 0..15) ----
    // lane handles channel pair (2*lane, 2*lane+1)
    const int c0 = 2 * lane;
    for (int nn = 0; nn < 16; ++nn) {
        int n = w * 16 + nn;
        size_t kb = ((size_t)bt1 * N1C + n0 + n) * 3;
        unsigned int u0 = nbr[kb], u1 = nbr[kb + 1], u2 = nbr[kb + 2];
        const unsigned short* p0 = tt + (size_t)(u0 >> 16) * CTC;
        const unsigned short* p1 = tt + (size_t)(u1 >> 16) * CTC;
        const unsigned short* p2 = tt + (size_t)(u2 >> 16) * CTC;
        float q0 = __half2float(__ushort_as_half((unsigned short)(u0 & 0xffffu)));
        float q1 = __half2float(__ushort_as_half((unsigned short)(u1 & 0xffffu)));
        float q2 = __half2float(__ushort_as_half((unsigned short)(u2 & 0xffffu)));
        unsigned int g0 = *(const unsigned int*)(p0 + c0);
        unsigned int g1 = *(const unsigned int*)(p1 + c0);
        unsigned int g2 = *(const unsigned int*)(p2 + c0);
        float vE = (bf16_to_f((unsigned short)(g0 & 0xffffu)) * q0
                  + bf16_to_f((unsigned short)(g1 & 0xffffu)) * q1)
                  + bf16_to_f((unsigned short)(g2 & 0xffffu)) * q2;
        float vO = (bf16_to_f((unsigned short)(g0 >> 16)) * q0
                  + bf16_to_f((unsigned short)(g1 >> 16)) * q1)
                  + bf16_to_f((unsigned short)(g2 >> 16)) * q2;
        int bi = (((c0 >> 3) * 64) + n) * 8 + (c0 & 7);   // even -> +1 adjacent
        unsigned short hE = bf16_hi(vE), hO = bf16_hi(vO);
        *(unsigned int*)&xh[bi] = (unsigned int)hE | ((unsigned int)hO << 16);
        unsigned short lE = bf16_hi(vE - bf16_to_f(hE));
        unsigned short lO = bf16_hi(vO - bf16_to_f(hO));
        *(unsigned int*)&xl[bi] = (unsigned int)lE | ((unsigned int)lO << 16);
    }
    __syncthreads();

    // ---- phase 1 GEMM: kst 0..3 (c8 0..15) ----
    for (int kst = 0; kst < 4; ++kst) {
        bf16x8 ah[4], al[4], bh[4], bl[4];
        #pragma unroll
        for (int mi = 0; mi < 4; ++mi) {
            int n = mi * 16 + l15;
            int c8 = kst * 4 + quad;
            ah[mi] = *(const bf16x8*)&xh[(c8 * 64 + n) * 8];
            al[mi] = *(const bf16x8*)&xl[(c8 * 64 + n) * 8];
        }
        #pragma unroll
        for (int oi = 0; oi < 4; ++oi) {
            int o = w * 64 + oi * 16 + l15;
            bh[oi] = *(const bf16x8*)(WsH + (size_t)o * 192 + kst * 32 + quad * 8);
            bl[oi] = *(const bf16x8*)(WsL + (size_t)o * 192 + kst * 32 + quad * 8);
        }
        #pragma unroll
        for (int mi = 0; mi < 4; ++mi)
            #pragma unroll
            for (int oi = 0; oi < 4; ++oi) {
                acc[mi][oi] = MFMA16(ah[mi], bh[oi], acc[mi][oi]);
                acc[mi][oi] = MFMA16(ah[mi], bl[oi], acc[mi][oi]);
                acc[mi][oi] = MFMA16(al[mi], bh[oi], acc[mi][oi]);
            }
    }
    __syncthreads();   // phase-1 reads done; buffer reusable

    // ---- phase 2 staging: original_features c=128..191 (c8' 0..7) ----
    {
        const float* ofp = ofeat + (size_t)bt1 * CORIGC * N1C;
        for (int i = 0; i < 16; ++i) {
            int idx = i * 256 + t;
            int cp = idx >> 6, n = idx & 63;   // cp = c-128 in 0..63
            float v = ofp[(size_t)cp * N1C + n0 + n];
            int bi = (((cp >> 3) * 64) + n) * 8 + (cp & 7);
            unsigned short h = bf16_hi(v);
            xh[bi] = h; xl[bi] = bf16_hi(v - bf16_to_f(h));
        }
    }
    __syncthreads();

    // ---- phase 2 GEMM: kst 4..5 (c8' 0..7) ----
    for (int kst = 4; kst < 6; ++kst) {
        bf16x8 ah[4], al[4], bh[4], bl[4];
        #pragma unroll
        for (int mi = 0; mi < 4; ++mi) {
            int n = mi * 16 + l15;
            int c8p = (kst - 4) * 4 + quad;
            ah[mi] = *(const bf16x8*)&xh[(c8p * 64 + n) * 8];
            al[mi] = *(const bf16x8*)&xl[(c8p * 64 + n) * 8];
        }
        #pragma unroll
        for (int oi = 0; oi < 4; ++oi) {
            int o = w * 64 + oi * 16 + l15;
            bh[oi] = *(const bf16x8*)(WsH + (size_t)o * 192 + kst * 32 + quad * 8);
            bl[oi] = *(const bf16x8*)(WsL + (size_t)o * 192 + kst * 32 + quad * 8);
        }
        #pragma unroll
        for (int mi = 0; mi < 4; ++mi)
            #pragma unroll
            for (int oi = 0; oi < 4; ++oi) {
                acc[mi][oi] = MFMA16(ah[mi], bh[oi], acc[mi][oi]);
                acc[mi][oi] = MFMA16(ah[mi], bl[oi], acc[mi][oi]);
                acc[mi][oi] = MFMA16(al[mi], bh[oi], acc[mi][oi]);
            }
    }

    float* outp = out + OUT_XYZ_SIZE + (size_t)bt1 * CSC * N1C;
    #pragma unroll
    for (int oi = 0; oi < 4; ++oi) {
        int o = w * 64 + oi * 16 + l15;
        float sc = bnp[o], sh = bnp[CSC + o];
        #pragma unroll
        for (int mi = 0; mi < 4; ++mi) {
            int nb = n0 + mi * 16 + quad * 4;
            f32x4 y;
            y[0] = fmaxf(acc[mi][oi][0] * sc + sh, 0.f);
            y[1] = fmaxf(acc[mi][oi][1] * sc + sh, 0.f);
            y[2] = fmaxf(acc[mi][oi][2] * sc + sh, 0.f);
            y[3] = fmaxf(acc[mi][oi][3] * sc + sh, 0.f);
            *(f32x4*)&outp[(size_t)o * N1C + nb] = y;
        }
    }
}

// ---------------------------------------------------------------------------
extern "C" void kernel_launch(void* const* d_in, const int* in_sizes, int n_in,
                              void* d_out, int out_size, void* d_ws, size_t ws_size,
                              hipStream_t stream) {
    const float* xyzs  = (const float*)d_in[0];
    const float* oxyz  = (const float*)d_in[1];
    const float* feat  = (const float*)d_in[2];
    const float* ofeat = (const float*)d_in[3];
    const float* Wt0   = (const float*)d_in[4];
    const float* Wt1   = (const float*)d_in[5];
    const float* Wsm   = (const float*)d_in[6];
    const float* gam   = (const float*)d_in[7];
    const float* bet   = (const float*)d_in[8];
    const float* mu    = (const float*)d_in[9];
    const float* var   = (const float*)d_in[10];
    float* out = (float*)d_out;
    char*  wsb = (char*)d_ws;

    unsigned short* tt  = (unsigned short*)(wsb + WS_TT_OFF);
    unsigned int*   nbr = (unsigned int*)(wsb + WS_NBR_OFF);
    unsigned short* WsH = (unsigned short*)(wsb + WS_W_OFF);
    unsigned short* WsL = WsH + 49152;
    unsigned short* W0H = WsL + 49152;
    unsigned short* W0L = W0H + 49152;
    unsigned short* W1H = W0L + 49152;
    unsigned short* W1L = W1H + 49152;
    float*          bnp = (float*)(wsb + WS_BNP_OFF);

    // Output 0: exact passthrough
    hipMemcpyAsync(out, oxyz, (size_t)OUT_XYZ_SIZE * sizeof(float),
                   hipMemcpyDeviceToDevice, stream);

    hipLaunchKernelGGL(prep_kernel, dim3(64), dim3(256), 0, stream,
                       Wsm, Wt0, Wt1, gam, bet, mu, var,
                       WsH, WsL, W0H, W0L, W1H, W1L, bnp);
    hipLaunchKernelGGL(tt_kernel, dim3(32, BB * L2C, KC), dim3(256), 0, stream,
                       feat, W0H, W0L, W1H, W1L, tt);
    hipLaunchKernelGGL(knn_kernel, dim3(128, BB * L1C), dim3(256), 0, stream,
                       xyzs, oxyz, nbr);
    hipLaunchKernelGGL(out_kernel, dim3(128, BB * L1C), dim3(256), 0, stream,
                       ofeat, WsH, WsL, tt, nbr, bnp, out);
}

// Round 11
// 415.094 us; speedup vs baseline: 1.5208x; 1.1316x over previous
//
#include <hip/hip_runtime.h>
#include <hip/hip_bf16.h>
#include <hip/hip_fp16.h>

// Problem constants
#define BB 2
#define L2C 4
#define N2C 2048
#define L1C 9
#define N1C 8192
#define CINC 128
#define CTC 128
#define CSC 256
#define CORIGC 64
#define KC 3

#define OUT_XYZ_SIZE (BB*L1C*N1C*3)
#define FLT_BIG     3.402823466e38f

// knn LDS: 1024-seed chunks, padded group stride (16 seeds + 4 pad = 80B)
#define CHUNK   1024
#define GSTRIDE 20
#define NGROUPS 64             // 1024 seeds / 16
#define LDSF    (NGROUPS * GSTRIDE)   // 1280 floats per array (5 KB)

typedef __attribute__((ext_vector_type(8))) short bf16x8;
typedef __attribute__((ext_vector_type(4))) float f32x4;
typedef __attribute__((ext_vector_type(2))) float f32x2;
typedef __attribute__((ext_vector_type(4))) unsigned short u16x4;

#define MFMA16(a,b,c) __builtin_amdgcn_mfma_f32_16x16x32_bf16((a),(b),(c),0,0,0)

// ws layout (bytes):
//  tt   bf16     @ 0          : 6,291,456 * 2 = 12,582,912
//  nbr  u32      @ 12,582,912 :   442,368 * 4 =  1,769,472   (idx16<<16 | half(w))
//  WsH/WsL/W0H/W0L/W1H/W1L bf16 @ 14,352,384 : 6 * 49,152 * 2 = 589,824
//  bnp  f32[512] @ 14,942,208 : 2,048
//  total 14,944,256
#define WS_TT_OFF   0
#define WS_NBR_OFF  12582912
#define WS_W_OFF    14352384
#define WS_BNP_OFF  14942208

__device__ __forceinline__ unsigned short bf16_hi(float v) {
    __hip_bfloat16 h = __float2bfloat16(v);
    return *(unsigned short*)&h;
}
__device__ __forceinline__ float bf16_to_f(unsigned short u) {
    unsigned int x = ((unsigned int)u) << 16;
    return __uint_as_float(x);
}

// Packed distance for 2 seeds. Seeds are stored NEGATED in LDS so the
// subtraction becomes an add (bitwise identical: a + (-x) == a - x).
// contract(off) + same association ((dx*dx + dy*dy) + dz*dz) keeps distances
// bit-identical to the original scalar kernel -> identical top-3 selection.
__device__ __forceinline__ f32x2 d2pk(f32x2 nx, f32x2 ny, f32x2 nz,
                                      f32x2 av0, f32x2 av1, f32x2 av2) {
    #pragma clang fp contract(off)
    f32x2 dx = av0 + nx;
    f32x2 dy = av1 + ny;
    f32x2 dz = av2 + nz;
    return (dx * dx + dy * dy) + dz * dz;
}

// ---------------------------------------------------------------------------
// Kernel P: hi/lo bf16 splits of Ws/Wt0/Wt1 (each 49152 elems) + BN fold.
__global__ __launch_bounds__(256) void prep_kernel(const float* __restrict__ Wsm,
                                                   const float* __restrict__ Wt0,
                                                   const float* __restrict__ Wt1,
                                                   const float* __restrict__ gam,
                                                   const float* __restrict__ bet,
                                                   const float* __restrict__ mu,
                                                   const float* __restrict__ var,
                                                   unsigned short* __restrict__ WsH,
                                                   unsigned short* __restrict__ WsL,
                                                   unsigned short* __restrict__ W0H,
                                                   unsigned short* __restrict__ W0L,
                                                   unsigned short* __restrict__ W1H,
                                                   unsigned short* __restrict__ W1L,
                                                   float* __restrict__ bnp) {
    for (int i = blockIdx.x * 256 + threadIdx.x; i < 49152; i += gridDim.x * 256) {
        float a = Wsm[i]; unsigned short h = bf16_hi(a);
        WsH[i] = h; WsL[i] = bf16_hi(a - bf16_to_f(h));
        float b = Wt0[i]; h = bf16_hi(b);
        W0H[i] = h; W0L[i] = bf16_hi(b - bf16_to_f(h));
        float c = Wt1[i]; h = bf16_hi(c);
        W1H[i] = h; W1L[i] = bf16_hi(c - bf16_to_f(h));
    }
    if (blockIdx.x == 0) {
        int o = threadIdx.x;
        float sc = gam[o] / sqrtf(var[o] + 1e-5f);
        bnp[o]       = sc;
        bnp[CSC + o] = bet[o] - mu[o] * sc;
    }
}

// ---------------------------------------------------------------------------
// Kernel 1 (MFMA): tt[slice][k][n2][c] = relu(W1[k] @ relu(W0[k] @ feat[slice]))
// k on blockIdx.z (independent iterations) -> 768 blocks = 3/CU.
__global__ __launch_bounds__(256) void tt_kernel(const float* __restrict__ feat,
                                                 const unsigned short* __restrict__ W0H,
                                                 const unsigned short* __restrict__ W0L,
                                                 const unsigned short* __restrict__ W1H,
                                                 const unsigned short* __restrict__ W1L,
                                                 unsigned short* __restrict__ tt) {
    __shared__ unsigned short Bh[16 * 64 * 8];   // feat tile hi  (16 KB)
    __shared__ unsigned short Bl[16 * 64 * 8];   // feat tile lo
    __shared__ unsigned short Hh[16 * 64 * 8];   // layer-1 output hi
    const int t     = threadIdx.x;
    const int slice = blockIdx.y;
    const int k     = blockIdx.z;
    const int n0    = blockIdx.x * 64;
    const int lane  = t & 63;
    const int w     = t >> 6;
    const int l15   = lane & 15;
    const int quad  = lane >> 4;

    const float* f = feat + (size_t)slice * CINC * N2C;
    for (int i = 0; i < 32; ++i) {
        int idx = i * 256 + t;
        int c = idx >> 6, n = idx & 63;
        float v = f[(size_t)c * N2C + n0 + n];
        unsigned short h = bf16_hi(v);
        int bi = (((c >> 3) * 64) + n) * 8 + (c & 7);
        Bh[bi] = h;
        Bl[bi] = bf16_hi(v - bf16_to_f(h));
    }
    __syncthreads();

    unsigned short* ttg = tt + (size_t)slice * KC * N2C * CTC;
    const f32x4 zero = {0.f, 0.f, 0.f, 0.f};

    // ---- layer 1 ----
    f32x4 acc[2][4];
    for (int oi = 0; oi < 2; ++oi)
        for (int ni = 0; ni < 4; ++ni) acc[oi][ni] = zero;
    {
        const unsigned short* AH = W0H + (size_t)k * CTC * CINC;
        const unsigned short* AL = W0L + (size_t)k * CTC * CINC;
        for (int kst = 0; kst < 4; ++kst) {
            bf16x8 ah[2], al[2], bh[4], bl[4];
            #pragma unroll
            for (int oi = 0; oi < 2; ++oi) {
                int o = 32 * w + oi * 16 + l15;
                ah[oi] = *(const bf16x8*)(AH + (size_t)o * CINC + kst * 32 + quad * 8);
                al[oi] = *(const bf16x8*)(AL + (size_t)o * CINC + kst * 32 + quad * 8);
            }
            #pragma unroll
            for (int ni = 0; ni < 4; ++ni) {
                int n = ni * 16 + l15;
                int c8 = kst * 4 + quad;
                bh[ni] = *(const bf16x8*)&Bh[(c8 * 64 + n) * 8];
                bl[ni] = *(const bf16x8*)&Bl[(c8 * 64 + n) * 8];
            }
            #pragma unroll
            for (int oi = 0; oi < 2; ++oi)
                #pragma unroll
                for (int ni = 0; ni < 4; ++ni) {
                    acc[oi][ni] = MFMA16(ah[oi], bh[ni], acc[oi][ni]);
                    acc[oi][ni] = MFMA16(ah[oi], bl[ni], acc[oi][ni]);
                    acc[oi][ni] = MFMA16(al[oi], bh[ni], acc[oi][ni]);
                }
        }
    }
    #pragma unroll
    for (int oi = 0; oi < 2; ++oi)
        #pragma unroll
        for (int ni = 0; ni < 4; ++ni) {
            int n = ni * 16 + l15;
            int obase = 32 * w + oi * 16 + quad * 4;
            int ch = obase >> 3, jj = obase & 7;
            unsigned short* dst = &Hh[(ch * 64 + n) * 8 + jj];
            dst[0] = bf16_hi(fmaxf(acc[oi][ni][0], 0.f));
            dst[1] = bf16_hi(fmaxf(acc[oi][ni][1], 0.f));
            dst[2] = bf16_hi(fmaxf(acc[oi][ni][2], 0.f));
            dst[3] = bf16_hi(fmaxf(acc[oi][ni][3], 0.f));
        }
    __syncthreads();

    // ---- layer 2 ----
    f32x4 acc2[2][4];
    for (int oi = 0; oi < 2; ++oi)
        for (int ni = 0; ni < 4; ++ni) acc2[oi][ni] = zero;
    {
        const unsigned short* AH = W1H + (size_t)k * CTC * CTC;
        const unsigned short* AL = W1L + (size_t)k * CTC * CTC;
        for (int kst = 0; kst < 4; ++kst) {
            bf16x8 ah[2], al[2], bh[4];
            #pragma unroll
            for (int oi = 0; oi < 2; ++oi) {
                int o = 32 * w + oi * 16 + l15;
                ah[oi] = *(const bf16x8*)(AH + (size_t)o * CTC + kst * 32 + quad * 8);
                al[oi] = *(const bf16x8*)(AL + (size_t)o * CTC + kst * 32 + quad * 8);
            }
            #pragma unroll
            for (int ni = 0; ni < 4; ++ni) {
                int n = ni * 16 + l15;
                int c8 = kst * 4 + quad;
                bh[ni] = *(const bf16x8*)&Hh[(c8 * 64 + n) * 8];
            }
            #pragma unroll
            for (int oi = 0; oi < 2; ++oi)
                #pragma unroll
                for (int ni = 0; ni < 4; ++ni) {
                    acc2[oi][ni] = MFMA16(ah[oi], bh[ni], acc2[oi][ni]);
                    acc2[oi][ni] = MFMA16(al[oi], bh[ni], acc2[oi][ni]);
                }
        }
    }
    // relu + bf16 store: tt[k][n2][o], 4 consecutive o per lane -> 8B store
    #pragma unroll
    for (int oi = 0; oi < 2; ++oi)
        #pragma unroll
        for (int ni = 0; ni < 4; ++ni) {
            int n2 = n0 + ni * 16 + l15;
            int obase = 32 * w + oi * 16 + quad * 4;
            u16x4 vv;
            vv[0] = bf16_hi(fmaxf(acc2[oi][ni][0], 0.f));
            vv[1] = bf16_hi(fmaxf(acc2[oi][ni][1], 0.f));
            vv[2] = bf16_hi(fmaxf(acc2[oi][ni][2], 0.f));
            vv[3] = bf16_hi(fmaxf(acc2[oi][ni][3], 0.f));
            *(u16x4*)&ttg[((size_t)k * N2C + n2) * CTC + obase] = vv;
        }
}

// ---------------------------------------------------------------------------
// Kernel 2: 3-NN, 4 threads per anchor. grid (128 tiles of 64 anchors, 18 bt1).
// v8: GLOBAL two-pass. Pass A (per chunk): group-min tree + ONE insert of
// (group_min, GLOBAL group base) into a cross-chunk top-3. Pass B runs ONCE
// at the end, re-reading the 3 winning groups (48 seeds) from global xyzs
// (196KB, L2-resident; 16B-aligned float4 loads since group bases are
// multiples of 16 seeds = 192B). ax-x == staged ax+(-x) bitwise; same
// contract-off association; groups processed ascending ==> selection remains
// bit-identical (v5 proof applies globally: dropped groups have min >= m3 and
// their tied seeds lose the index tiebreak since group-id order = idx order).
// Removes per-chunk pass-B work + its divergent (bank-conflicted) LDS reads.
__global__ __launch_bounds__(256, 8) void knn_kernel(const float* __restrict__ xyzs,
                                                     const float* __restrict__ oxyz,
                                                     unsigned int* __restrict__ nbr) {
    __shared__ __align__(16) float sx[LDSF];
    __shared__ __align__(16) float sy[LDSF];
    __shared__ __align__(16) float sz[LDSF];
    float* candd = sx;            // overlay after scan: [64][4][3] = 768 floats
    int*   candi = (int*)sy;
    const int t   = threadIdx.x;
    const int bt1 = blockIdx.y;
    const int b   = bt1 / L1C;
    const int t1  = bt1 % L1C + 1;
    int t2min = (t1 - 2) >> 1; if (t2min < 0) t2min = 0;
    int t2max = (t1 - 1) >> 1; if (t2max > 3) t2max = 3;
    const int S = (t2max - t2min + 1) * N2C;

    const int a  = t & 63;
    const int p  = t >> 6;
    const int n1 = blockIdx.x * 64 + a;
    const float* ap = oxyz + ((size_t)bt1 * N1C + n1) * 3;
    const float ax = ap[0], ay = ap[1], az = ap[2];
    const f32x2 ax2 = {ax, ax}, ay2 = {ay, ay}, az2 = {az, az};

    // cross-chunk top-3 (group_min, global group seed-base)
    float gm0 = FLT_BIG, gm1 = FLT_BIG, gm2 = FLT_BIG;
    int   gg0 = 0, gg1 = 0, gg2 = 0;

    for (int cb = 0; cb < S; cb += CHUNK) {
        if (cb) __syncthreads();            // previous chunk fully consumed
        {
            int t2  = t2min + (cb >> 11);   // CHUNK divides plane size
            int off = cb & (N2C - 1);
            const float* base = xyzs + ((size_t)(b * L2C + t2) * N2C + off) * 3;
            for (int s = t; s < CHUNK; s += 256) {
                const float* pp = base + (size_t)s * 3;
                int li = (s >> 4) * GSTRIDE + (s & 15);
                sx[li] = -pp[0]; sy[li] = -pp[1]; sz[li] = -pp[2];
            }
        }
        __syncthreads();

        const int g0i = p * 16;             // this thread's 16 groups

        // ---- pass A: fold (group_min, global base) into cross-chunk top-3 ----
        for (int g = g0i; g < g0i + 16; ++g) {
            const int gb = g * GSTRIDE;
            f32x2 dd[8];
            #pragma unroll
            for (int q = 0; q < 4; ++q) {
                float4 X = ((const float4*)&sx[gb])[q];
                float4 Y = ((const float4*)&sy[gb])[q];
                float4 Z = ((const float4*)&sz[gb])[q];
                f32x2 xlo = {X.x, X.y}, xhi = {X.z, X.w};
                f32x2 ylo = {Y.x, Y.y}, yhi = {Y.z, Y.w};
                f32x2 zlo = {Z.x, Z.y}, zhi = {Z.z, Z.w};
                dd[2 * q]     = d2pk(xlo, ylo, zlo, ax2, ay2, az2);
                dd[2 * q + 1] = d2pk(xhi, yhi, zhi, ax2, ay2, az2);
            }
            float e0 = fminf(dd[0][0], dd[0][1]);
            float e1 = fminf(dd[1][0], dd[1][1]);
            float e2 = fminf(dd[2][0], dd[2][1]);
            float e3 = fminf(dd[3][0], dd[3][1]);
            float e4 = fminf(dd[4][0], dd[4][1]);
            float e5 = fminf(dd[5][0], dd[5][1]);
            float e6 = fminf(dd[6][0], dd[6][1]);
            float e7 = fminf(dd[7][0], dd[7][1]);
            float f0 = fminf(e0, e1), f1 = fminf(e2, e3);
            float f2 = fminf(e4, e5), f3 = fminf(e6, e7);
            float m  = fminf(fminf(f0, f1), fminf(f2, f3));
            // branchless group insert (strict <); groups processed in ascending
            // global id across chunks -> earliest kept on ties
            int sb = cb + (g << 4);
            bool c0 = m < gm0, c1 = m < gm1, c2 = m < gm2;
            int ns0 = c0 ? sb  : gg0;
            int ns1 = c0 ? gg0 : (c1 ? sb : gg1);
            int ns2 = c1 ? gg1 : (c2 ? sb : gg2);
            float nm0 = fminf(gm0, m);
            float nm1 = __builtin_amdgcn_fmed3f(gm0, gm1, m);
            float nm2 = __builtin_amdgcn_fmed3f(gm1, gm2, m);
            gm0 = nm0; gm1 = nm1; gm2 = nm2;
            gg0 = ns0; gg1 = ns1; gg2 = ns2;
        }
    }

    // ---- pass B (once): exact per-seed insert over 3 winning groups, read
    // from GLOBAL xyzs (L2-resident). Groups ascending by global base.
    int lo01 = min(gg0, gg1), hi01 = max(gg0, gg1);
    int gA = min(lo01, gg2);
    int gC = max(hi01, gg2);
    int gB = (gg0 + gg1 + gg2) - gA - gC;

    float b0 = FLT_BIG, b1 = FLT_BIG, b2 = FLT_BIG;
    int   i0 = 0, i1 = 0, i2 = 0;

    #pragma unroll
    for (int v = 0; v < 3; ++v) {
        int sb = (v == 0) ? gA : ((v == 1) ? gB : gC);
        int t2  = t2min + (sb >> 11);
        int n2b = sb & (N2C - 1);
        const float* gpf = xyzs + ((size_t)(b * L2C + t2) * N2C + n2b) * 3;
        const float4* gp = (const float4*)gpf;   // 192B-multiple offset -> aligned
        #pragma unroll
        for (int hg = 0; hg < 2; ++hg) {
            float4 q0 = gp[hg * 6 + 0], q1 = gp[hg * 6 + 1], q2 = gp[hg * 6 + 2];
            float4 q3 = gp[hg * 6 + 3], q4 = gp[hg * 6 + 4], q5 = gp[hg * 6 + 5];
            float xs[8] = {q0.x, q0.w, q1.z, q2.y, q3.x, q3.w, q4.z, q5.y};
            float ys[8] = {q0.y, q1.x, q1.w, q2.z, q3.y, q4.x, q4.w, q5.z};
            float zs[8] = {q0.z, q1.y, q2.x, q2.w, q3.z, q4.y, q5.x, q5.w};
            #pragma unroll
            for (int j = 0; j < 8; ++j) {
                float d;
                {
                    #pragma clang fp contract(off)
                    float dx = ax - xs[j], dy = ay - ys[j], dz = az - zs[j];
                    d = (dx * dx + dy * dy) + dz * dz;
                }
                int s = sb + hg * 8 + j;
                bool c0 = d < b0, c1 = d < b1, c2 = d < b2;
                int ni0 = c0 ? s  : i0;
                int ni1 = c0 ? i0 : (c1 ? s : i1);
                int ni2 = c1 ? i1 : (c2 ? s : i2);
                float nb0 = fminf(b0, d);
                float nb1 = __builtin_amdgcn_fmed3f(b0, b1, d);
                float nb2 = __builtin_amdgcn_fmed3f(b1, b2, d);
                b0 = nb0; b1 = nb1; b2 = nb2;
                i0 = ni0; i1 = ni1; i2 = ni2;
            }
        }
    }
    __syncthreads();   // all pass-A LDS reads done; sx/sy reusable

    candd[(a * 4 + p) * 3 + 0] = b0; candi[(a * 4 + p) * 3 + 0] = i0;
    candd[(a * 4 + p) * 3 + 1] = b1; candi[(a * 4 + p) * 3 + 1] = i1;
    candd[(a * 4 + p) * 3 + 2] = b2; candi[(a * 4 + p) * 3 + 2] = i2;
    __syncthreads();

    if (t < 64) {
        float dd[12]; int ii[12];
        for (int q = 0; q < 12; ++q) { dd[q] = candd[t * 12 + q]; ii[q] = candi[t * 12 + q]; }
        for (int x = 1; x < 12; ++x) {
            float dv = dd[x]; int iv = ii[x]; int y = x - 1;
            while (y >= 0 && (dd[y] > dv || (dd[y] == dv && ii[y] > iv))) {
                dd[y + 1] = dd[y]; ii[y + 1] = ii[y]; --y;
            }
            dd[y + 1] = dv; ii[y + 1] = iv;
        }
        float w0 = 1.f / (dd[0] + 1e-8f);
        float w1 = 1.f / (dd[1] + 1e-8f);
        float w2 = 1.f / (dd[2] + 1e-8f);
        float wsum = (w0 + w1) + w2;
        float wv[3] = { w0 / wsum, w1 / wsum, w2 / wsum };
        size_t base = ((size_t)bt1 * N1C + blockIdx.x * 64 + t) * 3;
        #pragma unroll
        for (int j = 0; j < 3; ++j) {
            int s  = ii[j];
            int t2 = t2min + (s >> 11);
            int n2 = s & 2047;
            int kidx = t1 - 2 * t2 - 1;
            unsigned int idx16 = (unsigned int)(((b * L2C + t2) * KC + kidx) * N2C + n2);
            unsigned short hb = __half_as_ushort(__float2half(wv[j]));
            nbr[base + j] = (idx16 << 16) | (unsigned int)hb;
        }
    }
}

// ---------------------------------------------------------------------------
// Kernel 3 (MFMA): gather-interp + concat + GEMM(o=256, k=192) + BN + ReLU.
// v4 = v3 (K-phase-split, no min-waves bound) + unroll-4 on the interp loop:
// batches 12 independent gathers in flight (was 3) to hide L2/L3 latency --
// out is ~3x off its 49us memory roofline (round-9 spill arithmetic => ~145us
// healthy), i.e. latency-bound in the nbr->tt gather chain. Iterations touch
// disjoint rows, no FP accumulation across iterations -> bit-identical.
__global__ __launch_bounds__(256) void out_kernel(const float* __restrict__ ofeat,
                                                  const unsigned short* __restrict__ WsH,
                                                  const unsigned short* __restrict__ WsL,
                                                  const unsigned short* __restrict__ tt,
                                                  const unsigned int* __restrict__ nbr,
                                                  const float* __restrict__ bnp,
                                                  float* __restrict__ out) {
    __shared__ unsigned short xh[16 * 64 * 8];   // x tile hi, K-blocked (16 KB)
    __shared__ unsigned short xl[16 * 64 * 8];   // x tile lo
    const int t    = threadIdx.x;
    const int bt1  = blockIdx.y;
    const int n0   = blockIdx.x * 64;
    const int w    = t >> 6;
    const int lane = t & 63;
    const int l15  = lane & 15;
    const int quad = lane >> 4;

    const f32x4 zero = {0.f, 0.f, 0.f, 0.f};
    f32x4 acc[4][4];
    for (int mi = 0; mi < 4; ++mi)
        for (int oi = 0; oi < 4; ++oi) acc[mi][oi] = zero;

    // ---- phase 1 staging: interp rows c=0..127 (c8 0..15) ----
    // lane handles channel pair (2*lane, 2*lane+1)
    const int c0 = 2 * lane;
    #pragma unroll 4
    for (int nn = 0; nn < 16; ++nn) {
        int n = w * 16 + nn;
        size_t kb = ((size_t)bt1 * N1C + n0 + n) * 3;
        unsigned int u0 = nbr[kb], u1 = nbr[kb + 1], u2 = nbr[kb + 2];
        const unsigned short* p0 = tt + (size_t)(u0 >> 16) * CTC;
        const unsigned short* p1 = tt + (size_t)(u1 >> 16) * CTC;
        const unsigned short* p2 = tt + (size_t)(u2 >> 16) * CTC;
        float q0 = __half2float(__ushort_as_half((unsigned short)(u0 & 0xffffu)));
        float q1 = __half2float(__ushort_as_half((unsigned short)(u1 & 0xffffu)));
        float q2 = __half2float(__ushort_as_half((unsigned short)(u2 & 0xffffu)));
        unsigned int g0 = *(const unsigned int*)(p0 + c0);
        unsigned int g1 = *(const unsigned int*)(p1 + c0);
        unsigned int g2 = *(const unsigned int*)(p2 + c0);
        float vE = (bf16_to_f((unsigned short)(g0 & 0xffffu)) * q0
                  + bf16_to_f((unsigned short)(g1 & 0xffffu)) * q1)
                  + bf16_to_f((unsigned short)(g2 & 0xffffu)) * q2;
        float vO = (bf16_to_f((unsigned short)(g0 >> 16)) * q0
                  + bf16_to_f((unsigned short)(g1 >> 16)) * q1)
                  + bf16_to_f((unsigned short)(g2 >> 16)) * q2;
        int bi = (((c0 >> 3) * 64) + n) * 8 + (c0 & 7);   // even -> +1 adjacent
        unsigned short hE = bf16_hi(vE), hO = bf16_hi(vO);
        *(unsigned int*)&xh[bi] = (unsigned int)hE | ((unsigned int)hO << 16);
        unsigned short lE = bf16_hi(vE - bf16_to_f(hE));
        unsigned short lO = bf16_hi(vO - bf16_to_f(hO));
        *(unsigned int*)&xl[bi] = (unsigned int)lE | ((unsigned int)lO << 16);
    }
    __syncthreads();

    // ---- phase 1 GEMM: kst 0..3 (c8 0..15) ----
    for (int kst = 0; kst < 4; ++kst) {
        bf16x8 ah[4], al[4], bh[4], bl[4];
        #pragma unroll
        for (int mi = 0; mi < 4; ++mi) {
            int n = mi * 16 + l15;
            int c8 = kst * 4 + quad;
            ah[mi] = *(const bf16x8*)&xh[(c8 * 64 + n) * 8];
            al[mi] = *(const bf16x8*)&xl[(c8 * 64 + n) * 8];
        }
        #pragma unroll
        for (int oi = 0; oi < 4; ++oi) {
            int o = w * 64 + oi * 16 + l15;
            bh[oi] = *(const bf16x8*)(WsH + (size_t)o * 192 + kst * 32 + quad * 8);
            bl[oi] = *(const bf16x8*)(WsL + (size_t)o * 192 + kst * 32 + quad * 8);
        }
        #pragma unroll
        for (int mi = 0; mi < 4; ++mi)
            #pragma unroll
            for (int oi = 0; oi < 4; ++oi) {
                acc[mi][oi] = MFMA16(ah[mi], bh[oi], acc[mi][oi]);
                acc[mi][oi] = MFMA16(ah[mi], bl[oi], acc[mi][oi]);
                acc[mi][oi] = MFMA16(al[mi], bh[oi], acc[mi][oi]);
            }
    }
    __syncthreads();   // phase-1 reads done; buffer reusable

    // ---- phase 2 staging: original_features c=128..191 (c8' 0..7) ----
    {
        const float* ofp = ofeat + (size_t)bt1 * CORIGC * N1C;
        #pragma unroll 4
        for (int i = 0; i < 16; ++i) {
            int idx = i * 256 + t;
            int cp = idx >> 6, n = idx & 63;   // cp = c-128 in 0..63
            float v = ofp[(size_t)cp * N1C + n0 + n];
            int bi = (((cp >> 3) * 64) + n) * 8 + (cp & 7);
            unsigned short h = bf16_hi(v);
            xh[bi] = h; xl[bi] = bf16_hi(v - bf16_to_f(h));
        }
    }
    __syncthreads();

    // ---- phase 2 GEMM: kst 4..5 (c8' 0..7) ----
    for (int kst = 4; kst < 6; ++kst) {
        bf16x8 ah[4], al[4], bh[4], bl[4];
        #pragma unroll
        for (int mi = 0; mi < 4; ++mi) {
            int n = mi * 16 + l15;
            int c8p = (kst - 4) * 4 + quad;
            ah[mi] = *(const bf16x8*)&xh[(c8p * 64 + n) * 8];
            al[mi] = *(const bf16x8*)&xl[(c8p * 64 + n) * 8];
        }
        #pragma unroll
        for (int oi = 0; oi < 4; ++oi) {
            int o = w * 64 + oi * 16 + l15;
            bh[oi] = *(const bf16x8*)(WsH + (size_t)o * 192 + kst * 32 + quad * 8);
            bl[oi] = *(const bf16x8*)(WsL + (size_t)o * 192 + kst * 32 + quad * 8);
        }
        #pragma unroll
        for (int mi = 0; mi < 4; ++mi)
            #pragma unroll
            for (int oi = 0; oi < 4; ++oi) {
                acc[mi][oi] = MFMA16(ah[mi], bh[oi], acc[mi][oi]);
                acc[mi][oi] = MFMA16(ah[mi], bl[oi], acc[mi][oi]);
                acc[mi][oi] = MFMA16(al[mi], bh[oi], acc[mi][oi]);
            }
    }

    float* outp = out + OUT_XYZ_SIZE + (size_t)bt1 * CSC * N1C;
    #pragma unroll
    for (int oi = 0; oi < 4; ++oi) {
        int o = w * 64 + oi * 16 + l15;
        float sc = bnp[o], sh = bnp[CSC + o];
        #pragma unroll
        for (int mi = 0; mi < 4; ++mi) {
            int nb = n0 + mi * 16 + quad * 4;
            f32x4 y;
            y[0] = fmaxf(acc[mi][oi][0] * sc + sh, 0.f);
            y[1] = fmaxf(acc[mi][oi][1] * sc + sh, 0.f);
            y[2] = fmaxf(acc[mi][oi][2] * sc + sh, 0.f);
            y[3] = fmaxf(acc[mi][oi][3] * sc + sh, 0.f);
            *(f32x4*)&outp[(size_t)o * N1C + nb] = y;
        }
    }
}

// ---------------------------------------------------------------------------
extern "C" void kernel_launch(void* const* d_in, const int* in_sizes, int n_in,
                              void* d_out, int out_size, void* d_ws, size_t ws_size,
                              hipStream_t stream) {
    const float* xyzs  = (const float*)d_in[0];
    const float* oxyz  = (const float*)d_in[1];
    const float* feat  = (const float*)d_in[2];
    const float* ofeat = (const float*)d_in[3];
    const float* Wt0   = (const float*)d_in[4];
    const float* Wt1   = (const float*)d_in[5];
    const float* Wsm   = (const float*)d_in[6];
    const float* gam   = (const float*)d_in[7];
    const float* bet   = (const float*)d_in[8];
    const float* mu    = (const float*)d_in[9];
    const float* var   = (const float*)d_in[10];
    float* out = (float*)d_out;
    char*  wsb = (char*)d_ws;

    unsigned short* tt  = (unsigned short*)(wsb + WS_TT_OFF);
    unsigned int*   nbr = (unsigned int*)(wsb + WS_NBR_OFF);
    unsigned short* WsH = (unsigned short*)(wsb + WS_W_OFF);
    unsigned short* WsL = WsH + 49152;
    unsigned short* W0H = WsL + 49152;
    unsigned short* W0L = W0H + 49152;
    unsigned short* W1H = W0L + 49152;
    unsigned short* W1L = W1H + 49152;
    float*          bnp = (float*)(wsb + WS_BNP_OFF);

    // Output 0: exact passthrough
    hipMemcpyAsync(out, oxyz, (size_t)OUT_XYZ_SIZE * sizeof(float),
                   hipMemcpyDeviceToDevice, stream);

    hipLaunchKernelGGL(prep_kernel, dim3(64), dim3(256), 0, stream,
                       Wsm, Wt0, Wt1, gam, bet, mu, var,
                       WsH, WsL, W0H, W0L, W1H, W1L, bnp);
    hipLaunchKernelGGL(tt_kernel, dim3(32, BB * L2C, KC), dim3(256), 0, stream,
                       feat, W0H, W0L, W1H, W1L, tt);
    hipLaunchKernelGGL(knn_kernel, dim3(128, BB * L1C), dim3(256), 0, stream,
                       xyzs, oxyz, nbr);
    hipLaunchKernelGGL(out_kernel, dim3(128, BB * L1C), dim3(256), 0, stream,
                       ofeat, WsH, WsL, tt, nbr, bnp, out);
}

// Round 12
// 403.909 us; speedup vs baseline: 1.5629x; 1.0277x over previous
//
#include <hip/hip_runtime.h>
#include <hip/hip_bf16.h>
#include <hip/hip_fp16.h>

// Problem constants
#define BB 2
#define L2C 4
#define N2C 2048
#define L1C 9
#define N1C 8192
#define CINC 128
#define CTC 128
#define CSC 256
#define CORIGC 64
#define KC 3

#define OUT_XYZ_SIZE (BB*L1C*N1C*3)
#define FLT_BIG     3.402823466e38f

// knn LDS: 1024-seed chunks, padded group stride (16 seeds + 4 pad = 80B)
#define CHUNK   1024
#define GSTRIDE 20
#define NGROUPS 64             // 1024 seeds / 16
#define LDSF    (NGROUPS * GSTRIDE)   // 1280 floats per array (5 KB)

typedef __attribute__((ext_vector_type(8))) short bf16x8;
typedef __attribute__((ext_vector_type(4))) float f32x4;
typedef __attribute__((ext_vector_type(2))) float f32x2;
typedef __attribute__((ext_vector_type(4))) unsigned short u16x4;

#define MFMA16(a,b,c) __builtin_amdgcn_mfma_f32_16x16x32_bf16((a),(b),(c),0,0,0)

// ws layout (bytes):
//  tt   bf16     @ 0          : 6,291,456 * 2 = 12,582,912
//  nbr  u32      @ 12,582,912 :   442,368 * 4 =  1,769,472   (idx16<<16 | half(w))
//  WsH/WsL/W0H/W0L/W1H/W1L bf16 @ 14,352,384 : 6 * 49,152 * 2 = 589,824
//  bnp  f32[512] @ 14,942,208 : 2,048
//  total 14,944,256
#define WS_TT_OFF   0
#define WS_NBR_OFF  12582912
#define WS_W_OFF    14352384
#define WS_BNP_OFF  14942208

__device__ __forceinline__ unsigned short bf16_hi(float v) {
    __hip_bfloat16 h = __float2bfloat16(v);
    return *(unsigned short*)&h;
}
__device__ __forceinline__ float bf16_to_f(unsigned short u) {
    unsigned int x = ((unsigned int)u) << 16;
    return __uint_as_float(x);
}

// Packed distance for 2 seeds. Seeds are stored NEGATED in LDS so the
// subtraction becomes an add (bitwise identical: a + (-x) == a - x).
// contract(off) + same association ((dx*dx + dy*dy) + dz*dz) keeps distances
// bit-identical to the original scalar kernel -> identical top-3 selection.
__device__ __forceinline__ f32x2 d2pk(f32x2 nx, f32x2 ny, f32x2 nz,
                                      f32x2 av0, f32x2 av1, f32x2 av2) {
    #pragma clang fp contract(off)
    f32x2 dx = av0 + nx;
    f32x2 dy = av1 + ny;
    f32x2 dz = av2 + nz;
    return (dx * dx + dy * dy) + dz * dz;
}

// ---------------------------------------------------------------------------
// Kernel P: hi/lo bf16 splits of Ws/Wt0/Wt1 (each 49152 elems) + BN fold.
__global__ __launch_bounds__(256) void prep_kernel(const float* __restrict__ Wsm,
                                                   const float* __restrict__ Wt0,
                                                   const float* __restrict__ Wt1,
                                                   const float* __restrict__ gam,
                                                   const float* __restrict__ bet,
                                                   const float* __restrict__ mu,
                                                   const float* __restrict__ var,
                                                   unsigned short* __restrict__ WsH,
                                                   unsigned short* __restrict__ WsL,
                                                   unsigned short* __restrict__ W0H,
                                                   unsigned short* __restrict__ W0L,
                                                   unsigned short* __restrict__ W1H,
                                                   unsigned short* __restrict__ W1L,
                                                   float* __restrict__ bnp) {
    for (int i = blockIdx.x * 256 + threadIdx.x; i < 49152; i += gridDim.x * 256) {
        float a = Wsm[i]; unsigned short h = bf16_hi(a);
        WsH[i] = h; WsL[i] = bf16_hi(a - bf16_to_f(h));
        float b = Wt0[i]; h = bf16_hi(b);
        W0H[i] = h; W0L[i] = bf16_hi(b - bf16_to_f(h));
        float c = Wt1[i]; h = bf16_hi(c);
        W1H[i] = h; W1L[i] = bf16_hi(c - bf16_to_f(h));
    }
    if (blockIdx.x == 0) {
        int o = threadIdx.x;
        float sc = gam[o] / sqrtf(var[o] + 1e-5f);
        bnp[o]       = sc;
        bnp[CSC + o] = bet[o] - mu[o] * sc;
    }
}

// ---------------------------------------------------------------------------
// Kernel 1 (MFMA): tt[slice][k][n2][c] = relu(W1[k] @ relu(W0[k] @ feat[slice]))
// k on blockIdx.z (independent iterations) -> 768 blocks = 3/CU.
__global__ __launch_bounds__(256) void tt_kernel(const float* __restrict__ feat,
                                                 const unsigned short* __restrict__ W0H,
                                                 const unsigned short* __restrict__ W0L,
                                                 const unsigned short* __restrict__ W1H,
                                                 const unsigned short* __restrict__ W1L,
                                                 unsigned short* __restrict__ tt) {
    __shared__ unsigned short Bh[16 * 64 * 8];   // feat tile hi  (16 KB)
    __shared__ unsigned short Bl[16 * 64 * 8];   // feat tile lo
    __shared__ unsigned short Hh[16 * 64 * 8];   // layer-1 output hi
    const int t     = threadIdx.x;
    const int slice = blockIdx.y;
    const int k     = blockIdx.z;
    const int n0    = blockIdx.x * 64;
    const int lane  = t & 63;
    const int w     = t >> 6;
    const int l15   = lane & 15;
    const int quad  = lane >> 4;

    const float* f = feat + (size_t)slice * CINC * N2C;
    for (int i = 0; i < 32; ++i) {
        int idx = i * 256 + t;
        int c = idx >> 6, n = idx & 63;
        float v = f[(size_t)c * N2C + n0 + n];
        unsigned short h = bf16_hi(v);
        int bi = (((c >> 3) * 64) + n) * 8 + (c & 7);
        Bh[bi] = h;
        Bl[bi] = bf16_hi(v - bf16_to_f(h));
    }
    __syncthreads();

    unsigned short* ttg = tt + (size_t)slice * KC * N2C * CTC;
    const f32x4 zero = {0.f, 0.f, 0.f, 0.f};

    // ---- layer 1 ----
    f32x4 acc[2][4];
    for (int oi = 0; oi < 2; ++oi)
        for (int ni = 0; ni < 4; ++ni) acc[oi][ni] = zero;
    {
        const unsigned short* AH = W0H + (size_t)k * CTC * CINC;
        const unsigned short* AL = W0L + (size_t)k * CTC * CINC;
        for (int kst = 0; kst < 4; ++kst) {
            bf16x8 ah[2], al[2], bh[4], bl[4];
            #pragma unroll
            for (int oi = 0; oi < 2; ++oi) {
                int o = 32 * w + oi * 16 + l15;
                ah[oi] = *(const bf16x8*)(AH + (size_t)o * CINC + kst * 32 + quad * 8);
                al[oi] = *(const bf16x8*)(AL + (size_t)o * CINC + kst * 32 + quad * 8);
            }
            #pragma unroll
            for (int ni = 0; ni < 4; ++ni) {
                int n = ni * 16 + l15;
                int c8 = kst * 4 + quad;
                bh[ni] = *(const bf16x8*)&Bh[(c8 * 64 + n) * 8];
                bl[ni] = *(const bf16x8*)&Bl[(c8 * 64 + n) * 8];
            }
            #pragma unroll
            for (int oi = 0; oi < 2; ++oi)
                #pragma unroll
                for (int ni = 0; ni < 4; ++ni) {
                    acc[oi][ni] = MFMA16(ah[oi], bh[ni], acc[oi][ni]);
                    acc[oi][ni] = MFMA16(ah[oi], bl[ni], acc[oi][ni]);
                    acc[oi][ni] = MFMA16(al[oi], bh[ni], acc[oi][ni]);
                }
        }
    }
    #pragma unroll
    for (int oi = 0; oi < 2; ++oi)
        #pragma unroll
        for (int ni = 0; ni < 4; ++ni) {
            int n = ni * 16 + l15;
            int obase = 32 * w + oi * 16 + quad * 4;
            int ch = obase >> 3, jj = obase & 7;
            unsigned short* dst = &Hh[(ch * 64 + n) * 8 + jj];
            dst[0] = bf16_hi(fmaxf(acc[oi][ni][0], 0.f));
            dst[1] = bf16_hi(fmaxf(acc[oi][ni][1], 0.f));
            dst[2] = bf16_hi(fmaxf(acc[oi][ni][2], 0.f));
            dst[3] = bf16_hi(fmaxf(acc[oi][ni][3], 0.f));
        }
    __syncthreads();

    // ---- layer 2 ----
    f32x4 acc2[2][4];
    for (int oi = 0; oi < 2; ++oi)
        for (int ni = 0; ni < 4; ++ni) acc2[oi][ni] = zero;
    {
        const unsigned short* AH = W1H + (size_t)k * CTC * CTC;
        const unsigned short* AL = W1L + (size_t)k * CTC * CTC;
        for (int kst = 0; kst < 4; ++kst) {
            bf16x8 ah[2], al[2], bh[4];
            #pragma unroll
            for (int oi = 0; oi < 2; ++oi) {
                int o = 32 * w + oi * 16 + l15;
                ah[oi] = *(const bf16x8*)(AH + (size_t)o * CTC + kst * 32 + quad * 8);
                al[oi] = *(const bf16x8*)(AL + (size_t)o * CTC + kst * 32 + quad * 8);
            }
            #pragma unroll
            for (int ni = 0; ni < 4; ++ni) {
                int n = ni * 16 + l15;
                int c8 = kst * 4 + quad;
                bh[ni] = *(const bf16x8*)&Hh[(c8 * 64 + n) * 8];
            }
            #pragma unroll
            for (int oi = 0; oi < 2; ++oi)
                #pragma unroll
                for (int ni = 0; ni < 4; ++ni) {
                    acc2[oi][ni] = MFMA16(ah[oi], bh[ni], acc2[oi][ni]);
                    acc2[oi][ni] = MFMA16(al[oi], bh[ni], acc2[oi][ni]);
                }
        }
    }
    // relu + bf16 store: tt[k][n2][o], 4 consecutive o per lane -> 8B store
    #pragma unroll
    for (int oi = 0; oi < 2; ++oi)
        #pragma unroll
        for (int ni = 0; ni < 4; ++ni) {
            int n2 = n0 + ni * 16 + l15;
            int obase = 32 * w + oi * 16 + quad * 4;
            u16x4 vv;
            vv[0] = bf16_hi(fmaxf(acc2[oi][ni][0], 0.f));
            vv[1] = bf16_hi(fmaxf(acc2[oi][ni][1], 0.f));
            vv[2] = bf16_hi(fmaxf(acc2[oi][ni][2], 0.f));
            vv[3] = bf16_hi(fmaxf(acc2[oi][ni][3], 0.f));
            *(u16x4*)&ttg[((size_t)k * N2C + n2) * CTC + obase] = vv;
        }
}

// ---------------------------------------------------------------------------
// Kernel 2: 3-NN, 4 threads per anchor. grid (128 tiles of 64 anchors, 18 bt1).
// v9 = v8 (global two-pass) + HEAVY-FIRST dispatch order.
//  Round-11 PMC: Occupancy 47% -- grid 2304 = 9 blocks/CU vs 8-block cap,
//  and work is imbalanced (t1 in {3,5,7} scans S=4096, others S=2048).
//  Dispatch is blockIdx-linear (y-major), so remapping blockIdx.y to put the
//  six heavy bt1 planes first packs the tail with short blocks. Pure
//  scheduling change -> bit-identical results.
__global__ __launch_bounds__(256, 8) void knn_kernel(const float* __restrict__ xyzs,
                                                     const float* __restrict__ oxyz,
                                                     unsigned int* __restrict__ nbr) {
    __shared__ __align__(16) float sx[LDSF];
    __shared__ __align__(16) float sy[LDSF];
    __shared__ __align__(16) float sz[LDSF];
    float* candd = sx;            // overlay after scan: [64][4][3] = 768 floats
    int*   candi = (int*)sy;
    const int t   = threadIdx.x;
    // heavy bt1 (S=4096): {2,4,6,11,13,15} dispatched first
    static const int permv[18] = {2, 4, 6, 11, 13, 15,
                                  0, 1, 3, 5, 7, 8,
                                  9, 10, 12, 14, 16, 17};
    const int bt1 = permv[blockIdx.y];
    const int b   = bt1 / L1C;
    const int t1  = bt1 % L1C + 1;
    int t2min = (t1 - 2) >> 1; if (t2min < 0) t2min = 0;
    int t2max = (t1 - 1) >> 1; if (t2max > 3) t2max = 3;
    const int S = (t2max - t2min + 1) * N2C;

    const int a  = t & 63;
    const int p  = t >> 6;
    const int n1 = blockIdx.x * 64 + a;
    const float* ap = oxyz + ((size_t)bt1 * N1C + n1) * 3;
    const float ax = ap[0], ay = ap[1], az = ap[2];
    const f32x2 ax2 = {ax, ax}, ay2 = {ay, ay}, az2 = {az, az};

    // cross-chunk top-3 (group_min, global group seed-base)
    float gm0 = FLT_BIG, gm1 = FLT_BIG, gm2 = FLT_BIG;
    int   gg0 = 0, gg1 = 0, gg2 = 0;

    for (int cb = 0; cb < S; cb += CHUNK) {
        if (cb) __syncthreads();            // previous chunk fully consumed
        {
            int t2  = t2min + (cb >> 11);   // CHUNK divides plane size
            int off = cb & (N2C - 1);
            const float* base = xyzs + ((size_t)(b * L2C + t2) * N2C + off) * 3;
            for (int s = t; s < CHUNK; s += 256) {
                const float* pp = base + (size_t)s * 3;
                int li = (s >> 4) * GSTRIDE + (s & 15);
                sx[li] = -pp[0]; sy[li] = -pp[1]; sz[li] = -pp[2];
            }
        }
        __syncthreads();

        const int g0i = p * 16;             // this thread's 16 groups

        // ---- pass A: fold (group_min, global base) into cross-chunk top-3 ----
        for (int g = g0i; g < g0i + 16; ++g) {
            const int gb = g * GSTRIDE;
            f32x2 dd[8];
            #pragma unroll
            for (int q = 0; q < 4; ++q) {
                float4 X = ((const float4*)&sx[gb])[q];
                float4 Y = ((const float4*)&sy[gb])[q];
                float4 Z = ((const float4*)&sz[gb])[q];
                f32x2 xlo = {X.x, X.y}, xhi = {X.z, X.w};
                f32x2 ylo = {Y.x, Y.y}, yhi = {Y.z, Y.w};
                f32x2 zlo = {Z.x, Z.y}, zhi = {Z.z, Z.w};
                dd[2 * q]     = d2pk(xlo, ylo, zlo, ax2, ay2, az2);
                dd[2 * q + 1] = d2pk(xhi, yhi, zhi, ax2, ay2, az2);
            }
            float e0 = fminf(dd[0][0], dd[0][1]);
            float e1 = fminf(dd[1][0], dd[1][1]);
            float e2 = fminf(dd[2][0], dd[2][1]);
            float e3 = fminf(dd[3][0], dd[3][1]);
            float e4 = fminf(dd[4][0], dd[4][1]);
            float e5 = fminf(dd[5][0], dd[5][1]);
            float e6 = fminf(dd[6][0], dd[6][1]);
            float e7 = fminf(dd[7][0], dd[7][1]);
            float f0 = fminf(e0, e1), f1 = fminf(e2, e3);
            float f2 = fminf(e4, e5), f3 = fminf(e6, e7);
            float m  = fminf(fminf(f0, f1), fminf(f2, f3));
            // branchless group insert (strict <); groups processed in ascending
            // global id across chunks -> earliest kept on ties
            int sb = cb + (g << 4);
            bool c0 = m < gm0, c1 = m < gm1, c2 = m < gm2;
            int ns0 = c0 ? sb  : gg0;
            int ns1 = c0 ? gg0 : (c1 ? sb : gg1);
            int ns2 = c1 ? gg1 : (c2 ? sb : gg2);
            float nm0 = fminf(gm0, m);
            float nm1 = __builtin_amdgcn_fmed3f(gm0, gm1, m);
            float nm2 = __builtin_amdgcn_fmed3f(gm1, gm2, m);
            gm0 = nm0; gm1 = nm1; gm2 = nm2;
            gg0 = ns0; gg1 = ns1; gg2 = ns2;
        }
    }

    // ---- pass B (once): exact per-seed insert over 3 winning groups, read
    // from GLOBAL xyzs (L2-resident). Groups ascending by global base.
    int lo01 = min(gg0, gg1), hi01 = max(gg0, gg1);
    int gA = min(lo01, gg2);
    int gC = max(hi01, gg2);
    int gB = (gg0 + gg1 + gg2) - gA - gC;

    float b0 = FLT_BIG, b1 = FLT_BIG, b2 = FLT_BIG;
    int   i0 = 0, i1 = 0, i2 = 0;

    #pragma unroll
    for (int v = 0; v < 3; ++v) {
        int sb = (v == 0) ? gA : ((v == 1) ? gB : gC);
        int t2  = t2min + (sb >> 11);
        int n2b = sb & (N2C - 1);
        const float* gpf = xyzs + ((size_t)(b * L2C + t2) * N2C + n2b) * 3;
        const float4* gp = (const float4*)gpf;   // 192B-multiple offset -> aligned
        #pragma unroll
        for (int hg = 0; hg < 2; ++hg) {
            float4 q0 = gp[hg * 6 + 0], q1 = gp[hg * 6 + 1], q2 = gp[hg * 6 + 2];
            float4 q3 = gp[hg * 6 + 3], q4 = gp[hg * 6 + 4], q5 = gp[hg * 6 + 5];
            float xs[8] = {q0.x, q0.w, q1.z, q2.y, q3.x, q3.w, q4.z, q5.y};
            float ys[8] = {q0.y, q1.x, q1.w, q2.z, q3.y, q4.x, q4.w, q5.z};
            float zs[8] = {q0.z, q1.y, q2.x, q2.w, q3.z, q4.y, q5.x, q5.w};
            #pragma unroll
            for (int j = 0; j < 8; ++j) {
                float d;
                {
                    #pragma clang fp contract(off)
                    float dx = ax - xs[j], dy = ay - ys[j], dz = az - zs[j];
                    d = (dx * dx + dy * dy) + dz * dz;
                }
                int s = sb + hg * 8 + j;
                bool c0 = d < b0, c1 = d < b1, c2 = d < b2;
                int ni0 = c0 ? s  : i0;
                int ni1 = c0 ? i0 : (c1 ? s : i1);
                int ni2 = c1 ? i1 : (c2 ? s : i2);
                float nb0 = fminf(b0, d);
                float nb1 = __builtin_amdgcn_fmed3f(b0, b1, d);
                float nb2 = __builtin_amdgcn_fmed3f(b1, b2, d);
                b0 = nb0; b1 = nb1; b2 = nb2;
                i0 = ni0; i1 = ni1; i2 = ni2;
            }
        }
    }
    __syncthreads();   // all pass-A LDS reads done; sx/sy reusable

    candd[(a * 4 + p) * 3 + 0] = b0; candi[(a * 4 + p) * 3 + 0] = i0;
    candd[(a * 4 + p) * 3 + 1] = b1; candi[(a * 4 + p) * 3 + 1] = i1;
    candd[(a * 4 + p) * 3 + 2] = b2; candi[(a * 4 + p) * 3 + 2] = i2;
    __syncthreads();

    if (t < 64) {
        float dd[12]; int ii[12];
        for (int q = 0; q < 12; ++q) { dd[q] = candd[t * 12 + q]; ii[q] = candi[t * 12 + q]; }
        for (int x = 1; x < 12; ++x) {
            float dv = dd[x]; int iv = ii[x]; int y = x - 1;
            while (y >= 0 && (dd[y] > dv || (dd[y] == dv && ii[y] > iv))) {
                dd[y + 1] = dd[y]; ii[y + 1] = ii[y]; --y;
            }
            dd[y + 1] = dv; ii[y + 1] = iv;
        }
        float w0 = 1.f / (dd[0] + 1e-8f);
        float w1 = 1.f / (dd[1] + 1e-8f);
        float w2 = 1.f / (dd[2] + 1e-8f);
        float wsum = (w0 + w1) + w2;
        float wv[3] = { w0 / wsum, w1 / wsum, w2 / wsum };
        size_t base = ((size_t)bt1 * N1C + blockIdx.x * 64 + t) * 3;
        #pragma unroll
        for (int j = 0; j < 3; ++j) {
            int s  = ii[j];
            int t2 = t2min + (s >> 11);
            int n2 = s & 2047;
            int kidx = t1 - 2 * t2 - 1;
            unsigned int idx16 = (unsigned int)(((b * L2C + t2) * KC + kidx) * N2C + n2);
            unsigned short hb = __half_as_ushort(__float2half(wv[j]));
            nbr[base + j] = (idx16 << 16) | (unsigned int)hb;
        }
    }
}

// ---------------------------------------------------------------------------
// Kernel 3 (MFMA): gather-interp + concat + GEMM(o=256, k=192) + BN + ReLU.
// v5 = v4 + (i) interp unroll 4->8 (24 gathers in flight) and (ii) T14
// async-stage for ofeat: the 16 phase-2 loads are ISSUED right after interp
// staging, so their HBM latency hides under phase-1 GEMM; values land in
// registers and are written to LDS after the phase-1 barrier. Same values,
// same LDS slots -> bit-identical. No min-waves bound (round-9 spill lesson).
__global__ __launch_bounds__(256) void out_kernel(const float* __restrict__ ofeat,
                                                  const unsigned short* __restrict__ WsH,
                                                  const unsigned short* __restrict__ WsL,
                                                  const unsigned short* __restrict__ tt,
                                                  const unsigned int* __restrict__ nbr,
                                                  const float* __restrict__ bnp,
                                                  float* __restrict__ out) {
    __shared__ unsigned short xh[16 * 64 * 8];   // x tile hi, K-blocked (16 KB)
    __shared__ unsigned short xl[16 * 64 * 8];   // x tile lo
    const int t    = threadIdx.x;
    const int bt1  = blockIdx.y;
    const int n0   = blockIdx.x * 64;
    const int w    = t >> 6;
    const int lane = t & 63;
    const int l15  = lane & 15;
    const int quad = lane >> 4;

    const f32x4 zero = {0.f, 0.f, 0.f, 0.f};
    f32x4 acc[4][4];
    for (int mi = 0; mi < 4; ++mi)
        for (int oi = 0; oi < 4; ++oi) acc[mi][oi] = zero;

    // ---- phase 1 staging: interp rows c=0..127 (c8 0..15) ----
    // lane handles channel pair (2*lane, 2*lane+1)
    const int c0 = 2 * lane;
    #pragma unroll 8
    for (int nn = 0; nn < 16; ++nn) {
        int n = w * 16 + nn;
        size_t kb = ((size_t)bt1 * N1C + n0 + n) * 3;
        unsigned int u0 = nbr[kb], u1 = nbr[kb + 1], u2 = nbr[kb + 2];
        const unsigned short* p0 = tt + (size_t)(u0 >> 16) * CTC;
        const unsigned short* p1 = tt + (size_t)(u1 >> 16) * CTC;
        const unsigned short* p2 = tt + (size_t)(u2 >> 16) * CTC;
        float q0 = __half2float(__ushort_as_half((unsigned short)(u0 & 0xffffu)));
        float q1 = __half2float(__ushort_as_half((unsigned short)(u1 & 0xffffu)));
        float q2 = __half2float(__ushort_as_half((unsigned short)(u2 & 0xffffu)));
        unsigned int g0 = *(const unsigned int*)(p0 + c0);
        unsigned int g1 = *(const unsigned int*)(p1 + c0);
        unsigned int g2 = *(const unsigned int*)(p2 + c0);
        float vE = (bf16_to_f((unsigned short)(g0 & 0xffffu)) * q0
                  + bf16_to_f((unsigned short)(g1 & 0xffffu)) * q1)
                  + bf16_to_f((unsigned short)(g2 & 0xffffu)) * q2;
        float vO = (bf16_to_f((unsigned short)(g0 >> 16)) * q0
                  + bf16_to_f((unsigned short)(g1 >> 16)) * q1)
                  + bf16_to_f((unsigned short)(g2 >> 16)) * q2;
        int bi = (((c0 >> 3) * 64) + n) * 8 + (c0 & 7);   // even -> +1 adjacent
        unsigned short hE = bf16_hi(vE), hO = bf16_hi(vO);
        *(unsigned int*)&xh[bi] = (unsigned int)hE | ((unsigned int)hO << 16);
        unsigned short lE = bf16_hi(vE - bf16_to_f(hE));
        unsigned short lO = bf16_hi(vO - bf16_to_f(hO));
        *(unsigned int*)&xl[bi] = (unsigned int)lE | ((unsigned int)lO << 16);
    }

    // T14: issue phase-2 ofeat loads NOW -- latency hides under phase-1 GEMM.
    float pf[16];
    {
        const float* ofp = ofeat + (size_t)bt1 * CORIGC * N1C;
        #pragma unroll
        for (int i = 0; i < 16; ++i) {
            int idx = i * 256 + t;
            int cp = idx >> 6, n = idx & 63;   // cp = c-128 in 0..63
            pf[i] = ofp[(size_t)cp * N1C + n0 + n];
        }
    }
    __syncthreads();

    // ---- phase 1 GEMM: kst 0..3 (c8 0..15) ----
    for (int kst = 0; kst < 4; ++kst) {
        bf16x8 ah[4], al[4], bh[4], bl[4];
        #pragma unroll
        for (int mi = 0; mi < 4; ++mi) {
            int n = mi * 16 + l15;
            int c8 = kst * 4 + quad;
            ah[mi] = *(const bf16x8*)&xh[(c8 * 64 + n) * 8];
            al[mi] = *(const bf16x8*)&xl[(c8 * 64 + n) * 8];
        }
        #pragma unroll
        for (int oi = 0; oi < 4; ++oi) {
            int o = w * 64 + oi * 16 + l15;
            bh[oi] = *(const bf16x8*)(WsH + (size_t)o * 192 + kst * 32 + quad * 8);
            bl[oi] = *(const bf16x8*)(WsL + (size_t)o * 192 + kst * 32 + quad * 8);
        }
        #pragma unroll
        for (int mi = 0; mi < 4; ++mi)
            #pragma unroll
            for (int oi = 0; oi < 4; ++oi) {
                acc[mi][oi] = MFMA16(ah[mi], bh[oi], acc[mi][oi]);
                acc[mi][oi] = MFMA16(ah[mi], bl[oi], acc[mi][oi]);
                acc[mi][oi] = MFMA16(al[mi], bh[oi], acc[mi][oi]);
            }
    }
    __syncthreads();   // phase-1 reads done; buffer reusable

    // ---- phase 2 staging: original_features c=128..191 (c8' 0..7) ----
    {
        #pragma unroll
        for (int i = 0; i < 16; ++i) {
            int idx = i * 256 + t;
            int cp = idx >> 6, n = idx & 63;   // cp = c-128 in 0..63
            int bi = (((cp >> 3) * 64) + n) * 8 + (cp & 7);
            unsigned short h = bf16_hi(pf[i]);
            xh[bi] = h; xl[bi] = bf16_hi(pf[i] - bf16_to_f(h));
        }
    }
    __syncthreads();

    // ---- phase 2 GEMM: kst 4..5 (c8' 0..7) ----
    for (int kst = 4; kst < 6; ++kst) {
        bf16x8 ah[4], al[4], bh[4], bl[4];
        #pragma unroll
        for (int mi = 0; mi < 4; ++mi) {
            int n = mi * 16 + l15;
            int c8p = (kst - 4) * 4 + quad;
            ah[mi] = *(const bf16x8*)&xh[(c8p * 64 + n) * 8];
            al[mi] = *(const bf16x8*)&xl[(c8p * 64 + n) * 8];
        }
        #pragma unroll
        for (int oi = 0; oi < 4; ++oi) {
            int o = w * 64 + oi * 16 + l15;
            bh[oi] = *(const bf16x8*)(WsH + (size_t)o * 192 + kst * 32 + quad * 8);
            bl[oi] = *(const bf16x8*)(WsL + (size_t)o * 192 + kst * 32 + quad * 8);
        }
        #pragma unroll
        for (int mi = 0; mi < 4; ++mi)
            #pragma unroll
            for (int oi = 0; oi < 4; ++oi) {
                acc[mi][oi] = MFMA16(ah[mi], bh[oi], acc[mi][oi]);
                acc[mi][oi] = MFMA16(ah[mi], bl[oi], acc[mi][oi]);
                acc[mi][oi] = MFMA16(al[mi], bh[oi], acc[mi][oi]);
            }
    }

    float* outp = out + OUT_XYZ_SIZE + (size_t)bt1 * CSC * N1C;
    #pragma unroll
    for (int oi = 0; oi < 4; ++oi) {
        int o = w * 64 + oi * 16 + l15;
        float sc = bnp[o], sh = bnp[CSC + o];
        #pragma unroll
        for (int mi = 0; mi < 4; ++mi) {
            int nb = n0 + mi * 16 + quad * 4;
            f32x4 y;
            y[0] = fmaxf(acc[mi][oi][0] * sc + sh, 0.f);
            y[1] = fmaxf(acc[mi][oi][1] * sc + sh, 0.f);
            y[2] = fmaxf(acc[mi][oi][2] * sc + sh, 0.f);
            y[3] = fmaxf(acc[mi][oi][3] * sc + sh, 0.f);
            *(f32x4*)&outp[(size_t)o * N1C + nb] = y;
        }
    }
}

// ---------------------------------------------------------------------------
extern "C" void kernel_launch(void* const* d_in, const int* in_sizes, int n_in,
                              void* d_out, int out_size, void* d_ws, size_t ws_size,
                              hipStream_t stream) {
    const float* xyzs  = (const float*)d_in[0];
    const float* oxyz  = (const float*)d_in[1];
    const float* feat  = (const float*)d_in[2];
    const float* ofeat = (const float*)d_in[3];
    const float* Wt0   = (const float*)d_in[4];
    const float* Wt1   = (const float*)d_in[5];
    const float* Wsm   = (const float*)d_in[6];
    const float* gam   = (const float*)d_in[7];
    const float* bet   = (const float*)d_in[8];
    const float* mu    = (const float*)d_in[9];
    const float* var   = (const float*)d_in[10];
    float* out = (float*)d_out;
    char*  wsb = (char*)d_ws;

    unsigned short* tt  = (unsigned short*)(wsb + WS_TT_OFF);
    unsigned int*   nbr = (unsigned int*)(wsb + WS_NBR_OFF);
    unsigned short* WsH = (unsigned short*)(wsb + WS_W_OFF);
    unsigned short* WsL = WsH + 49152;
    unsigned short* W0H = WsL + 49152;
    unsigned short* W0L = W0H + 49152;
    unsigned short* W1H = W0L + 49152;
    unsigned short* W1L = W1H + 49152;
    float*          bnp = (float*)(wsb + WS_BNP_OFF);

    // Output 0: exact passthrough
    hipMemcpyAsync(out, oxyz, (size_t)OUT_XYZ_SIZE * sizeof(float),
                   hipMemcpyDeviceToDevice, stream);

    hipLaunchKernelGGL(prep_kernel, dim3(64), dim3(256), 0, stream,
                       Wsm, Wt0, Wt1, gam, bet, mu, var,
                       WsH, WsL, W0H, W0L, W1H, W1L, bnp);
    hipLaunchKernelGGL(tt_kernel, dim3(32, BB * L2C, KC), dim3(256), 0, stream,
                       feat, W0H, W0L, W1H, W1L, tt);
    hipLaunchKernelGGL(knn_kernel, dim3(128, 18), dim3(256), 0, stream,
                       xyzs, oxyz, nbr);
    hipLaunchKernelGGL(out_kernel, dim3(128, BB * L1C), dim3(256), 0, stream,
                       ofeat, WsH, WsL, tt, nbr, bnp, out);
}